// Round 2
// baseline (644.977 us; speedup 1.0000x reference)
//
#include <hip/hip_runtime.h>
#include <math.h>

#define NODES  131072   // B*N
#define NEDGE  1048576  // E
#define NB     64
#define NPERG  2048     // N
#define HID    128
#define K1V    512
#define K2V    128
#define N1     32768    // NB*K1V
#define N2     8192     // NB*K2V
#define ECAP   131072   // capacity for surviving edges (expected ~65536)

static __device__ __forceinline__ float frelu(float v) { return v > 0.f ? v : 0.f; }

// ---------------- stage 1 ----------------

__global__ void k_deg(const int* __restrict__ dst, float* __restrict__ deg, int E) {
    int e = blockIdx.x * blockDim.x + threadIdx.x;
    if (e < E) atomicAdd(&deg[dst[e]], 1.0f);
}

__global__ void k_dinv(const float* __restrict__ deg, float* __restrict__ dinv, int n) {
    int i = blockIdx.x * blockDim.x + threadIdx.x;
    if (i < n) dinv[i] = 1.0f / sqrtf(deg[i] + 1.0f);
}

__global__ void k_tagg(const int* __restrict__ src, const int* __restrict__ dst,
                       const float* __restrict__ dinv, const float* __restrict__ x,
                       float* __restrict__ t, int E) {
    int e = blockIdx.x * blockDim.x + threadIdx.x;
    if (e < E) {
        int s = src[e], d = dst[e];
        atomicAdd(&t[d], dinv[s] * dinv[d] * x[s]);
    }
}

// u = t + x/deg; s0 = sum_c relu(W1[c]*u + b1[c]) * sW1[c]; score init = s0/deg + sb1
__global__ void k_node1(const float* __restrict__ x, const float* __restrict__ deg,
                        float* __restrict__ t_u,
                        const float* __restrict__ W1, const float* __restrict__ b1,
                        const float* __restrict__ sW1, const float* __restrict__ sb1,
                        float* __restrict__ s01, float* __restrict__ sc1, int n) {
    __shared__ float w[HID], bb[HID], sw[HID];
    int tid = threadIdx.x;
    for (int i = tid; i < HID; i += blockDim.x) {
        w[i] = W1[i]; bb[i] = b1[i]; sw[i] = sW1[i];
    }
    __syncthreads();
    int i = blockIdx.x * blockDim.x + tid;
    if (i >= n) return;
    float dfull = deg[i] + 1.0f;
    float u = t_u[i] + x[i] / dfull;
    t_u[i] = u;
    float s = 0.f;
    #pragma unroll 8
    for (int c = 0; c < HID; c++) s += frelu(fmaf(w[c], u, bb[c])) * sw[c];
    s01[i] = s;
    sc1[i] = s / dfull + sb1[0];
}

__global__ void k_sagg(const int* __restrict__ src, const int* __restrict__ dst,
                       const float* __restrict__ dinv, const float* __restrict__ s0,
                       float* __restrict__ sc, int E) {
    int e = blockIdx.x * blockDim.x + threadIdx.x;
    if (e < E) {
        int s = src[e], d = dst[e];
        atomicAdd(&sc[d], dinv[s] * dinv[d] * s0[s]);
    }
}

// per-graph bitonic top-k (descending, tie -> lower index first, = lax.top_k)
template <int NPG, int KEEP, int THREADS>
__global__ __launch_bounds__(THREADS) void k_topk(const float* __restrict__ score,
                                                  int* __restrict__ perm,
                                                  int* __restrict__ nmap) {
    __shared__ float sv[NPG];
    __shared__ int   si[NPG];
    const int b = blockIdx.x, tid = threadIdx.x;
    for (int i = tid; i < NPG; i += THREADS) { sv[i] = score[b * NPG + i]; si[i] = i; }
    __syncthreads();
    for (int k = 2; k <= NPG; k <<= 1) {
        for (int j = k >> 1; j > 0; j >>= 1) {
            for (int t = tid; t < NPG / 2; t += THREADS) {
                int i = ((t & ~(j - 1)) << 1) | (t & (j - 1));
                int p = i | j;
                bool desc = ((i & k) == 0);
                float va = sv[i], vb = sv[p];
                int ia = si[i], ib = si[p];
                bool before = (va > vb) || (va == vb && ia < ib);
                if (before != desc) { sv[i] = vb; sv[p] = va; si[i] = ib; si[p] = ia; }
            }
            __syncthreads();
        }
    }
    for (int t = tid; t < KEEP; t += THREADS) {
        int node = b * NPG + si[t];
        perm[b * KEEP + t] = node;
        if (nmap) nmap[node] = b * KEEP + t;
    }
}

// h_pool1[j,c] = relu(W1[c]*u[i]+b1[c]) * tanh(score[i]),  i = perm[j]
__global__ void k_hpool1(const int* __restrict__ perm, const float* __restrict__ u,
                         const float* __restrict__ sc,
                         const float* __restrict__ W1, const float* __restrict__ b1,
                         float* __restrict__ hp) {
    int idx = blockIdx.x * blockDim.x + threadIdx.x;
    if (idx >= N1 * HID) return;
    int j = idx >> 7, c = idx & 127;
    int i = perm[j];
    float g = tanhf(sc[i]);
    hp[idx] = frelu(fmaf(W1[c], u[i], b1[c])) * g;
}

// readout: block=graph, thread=channel; max + mean over kper rows
__global__ void k_readout(const float* __restrict__ h, float* __restrict__ xo, int kper) {
    int b = blockIdx.x, c = threadIdx.x; // 128 threads
    const float* base = h + (size_t)b * kper * HID + c;
    float mx = -INFINITY, sm = 0.f;
    for (int j = 0; j < kper; j++) { float v = base[j * HID]; mx = fmaxf(mx, v); sm += v; }
    xo[b * 2 * HID + c] = mx;
    xo[b * 2 * HID + HID + c] = sm / (float)kper;
}

__global__ void k_compact(const int* __restrict__ src, const int* __restrict__ dst,
                          const int* __restrict__ nmap, int* __restrict__ src2,
                          int* __restrict__ dst2, int* __restrict__ ecnt, int E) {
    int e = blockIdx.x * blockDim.x + threadIdx.x;
    if (e < E) {
        int s2 = nmap[src[e]], d2 = nmap[dst[e]];
        if (s2 >= 0 && d2 >= 0) {
            int p = atomicAdd(ecnt, 1);
            if (p < ECAP) { src2[p] = s2; dst2[p] = d2; }
        }
    }
}

// ---------------- stage 2 ----------------

__global__ void k_deg2(const int* __restrict__ dst2, const int* __restrict__ ecnt,
                       float* __restrict__ deg2) {
    int ec = *ecnt;
    if (ec > ECAP) ec = ECAP;
    for (int e = blockIdx.x * blockDim.x + threadIdx.x; e < ec; e += gridDim.x * blockDim.x)
        atomicAdd(&deg2[dst2[e]], 1.0f);
}

// hw = hp @ W2  (f32), 32 rows per block staged in LDS
#define MM_ROWS 32
__global__ __launch_bounds__(256) void k_matmul(const float* __restrict__ hp,
                                                const float* __restrict__ W2,
                                                float* __restrict__ hw) {
    __shared__ float lh[MM_ROWS * HID];
    int row0 = blockIdx.x * MM_ROWS;
    int tid = threadIdx.x;
    for (int i = tid; i < MM_ROWS * HID; i += 256) lh[i] = hp[row0 * HID + i];
    __syncthreads();
    int c = tid & 127, half = tid >> 7;
    float acc[16];
    #pragma unroll
    for (int r = 0; r < 16; r++) acc[r] = 0.f;
    for (int k = 0; k < HID; k++) {
        float w = W2[k * HID + c];
        #pragma unroll
        for (int r = 0; r < 16; r++) acc[r] = fmaf(lh[(half * 16 + r) * HID + k], w, acc[r]);
    }
    #pragma unroll
    for (int r = 0; r < 16; r++) hw[(row0 + half * 16 + r) * HID + c] = acc[r];
}

// agg init with self-loop term hw * (1/deg)
__global__ void k_agginit(const float* __restrict__ hw, const float* __restrict__ deg2,
                          float* __restrict__ agg) {
    int idx = blockIdx.x * blockDim.x + threadIdx.x;
    if (idx >= N1 * HID) return;
    int i = idx >> 7;
    agg[idx] = hw[idx] / (deg2[i] + 1.0f);
}

// edge feature aggregation: one wave per edge, 2 channels per lane
__global__ void k_eagg(const int* __restrict__ src2, const int* __restrict__ dst2,
                       const int* __restrict__ ecnt, const float* __restrict__ dinv2,
                       const float* __restrict__ hw, float* __restrict__ agg) {
    int ec = *ecnt;
    if (ec > ECAP) ec = ECAP;
    int lane = threadIdx.x & 63;
    int epb = blockDim.x >> 6;
    int eslot = threadIdx.x >> 6;
    for (int e = blockIdx.x * epb + eslot; e < ec; e += gridDim.x * epb) {
        int s = src2[e], d = dst2[e];
        float nm = dinv2[s] * dinv2[d];
        float v0 = hw[s * HID + lane] * nm;
        float v1 = hw[s * HID + lane + 64] * nm;
        atomicAdd(&agg[d * HID + lane], v0);
        atomicAdd(&agg[d * HID + lane + 64], v1);
    }
}

// h2 = relu(agg + b2) in place
__global__ void k_bias_relu(float* __restrict__ agg, const float* __restrict__ b2) {
    int idx = blockIdx.x * blockDim.x + threadIdx.x;
    if (idx >= N1 * HID) return;
    agg[idx] = frelu(agg[idx] + b2[idx & 127]);
}

// s0_2 = h2 . sW2 (wave per node), score2 init = s0_2/deg + sb2
__global__ void k_score2(const float* __restrict__ h2, const float* __restrict__ sW2,
                         const float* __restrict__ sb2, const float* __restrict__ deg2,
                         float* __restrict__ s02, float* __restrict__ sc2) {
    int node = blockIdx.x * (blockDim.x >> 6) + (threadIdx.x >> 6);
    int lane = threadIdx.x & 63;
    if (node >= N1) return;
    float a = h2[node * HID + lane] * sW2[lane] +
              h2[node * HID + lane + 64] * sW2[lane + 64];
    #pragma unroll
    for (int o = 32; o > 0; o >>= 1) a += __shfl_down(a, o);
    if (lane == 0) {
        s02[node] = a;
        sc2[node] = a / (deg2[node] + 1.0f) + sb2[0];
    }
}

__global__ void k_sagg2(const int* __restrict__ src2, const int* __restrict__ dst2,
                        const int* __restrict__ ecnt, const float* __restrict__ dinv2,
                        const float* __restrict__ s02, float* __restrict__ sc2) {
    int ec = *ecnt;
    if (ec > ECAP) ec = ECAP;
    for (int e = blockIdx.x * blockDim.x + threadIdx.x; e < ec; e += gridDim.x * blockDim.x) {
        int s = src2[e], d = dst2[e];
        atomicAdd(&sc2[d], dinv2[s] * dinv2[d] * s02[s]);
    }
}

// readout 2 fused with gather * tanh gate (no materialized h_pool2)
__global__ void k_read2(const float* __restrict__ h2, const float* __restrict__ sc2,
                        const int* __restrict__ perm2, float* __restrict__ x2) {
    __shared__ int   pi[K2V];
    __shared__ float tl[K2V];
    int b = blockIdx.x, tid = threadIdx.x; // 128 threads
    int i2 = perm2[b * K2V + tid];
    pi[tid] = i2;
    tl[tid] = tanhf(sc2[i2]);
    __syncthreads();
    float mx = -INFINITY, sm = 0.f;
    for (int j = 0; j < K2V; j++) {
        float v = h2[pi[j] * HID + tid] * tl[j];
        mx = fmaxf(mx, v); sm += v;
    }
    x2[b * 2 * HID + tid] = mx;
    x2[b * 2 * HID + HID + tid] = sm / (float)K2V;
}

// ---------------- head ----------------
__global__ __launch_bounds__(128) void k_head(const float* __restrict__ x1,
                                              const float* __restrict__ x2,
                                              const float* __restrict__ gi,
                                              const float* __restrict__ l1W, const float* __restrict__ l1b,
                                              const float* __restrict__ l2W, const float* __restrict__ l2b,
                                              const float* __restrict__ l3W, const float* __restrict__ l3b,
                                              float* __restrict__ out) {
    __shared__ float z[266], z1[HID], z2[64], z3[32], red[2];
    int b = blockIdx.x, t = threadIdx.x; // 128 threads
    for (int i = t; i < 256; i += 128) z[i] = x1[b * 256 + i] + x2[b * 256 + i];
    if (t < 10) z[256 + t] = gi[b * 10 + t];
    __syncthreads();
    float acc = l1b[t];
    for (int k = 0; k < 266; k++) acc = fmaf(z[k], l1W[k * 128 + t], acc);
    z1[t] = frelu(acc);
    __syncthreads();
    if (t < 64) {
        float a2 = l2b[t];
        for (int k = 0; k < 128; k++) a2 = fmaf(z1[k], l2W[k * 64 + t], a2);
        z2[t] = frelu(a2);
    }
    __syncthreads();
    if (t < 32) {
        float a3 = l3b[t];
        for (int k = 0; k < 64; k++) a3 = fmaf(z2[k], l3W[k * 32 + t], a3);
        z3[t] = a3;
    }
    __syncthreads();
    if (t == 0) {
        float m = -INFINITY;
        for (int c = 0; c < 32; c++) m = fmaxf(m, z3[c]);
        float s = 0.f;
        for (int c = 0; c < 32; c++) s += expf(z3[c] - m);
        red[0] = m; red[1] = logf(s);
    }
    __syncthreads();
    if (t < 32) out[b * 32 + t] = z3[t] - red[0] - red[1];
}

// ---------------- launch ----------------

extern "C" void kernel_launch(void* const* d_in, const int* in_sizes, int n_in,
                              void* d_out, int out_size, void* d_ws, size_t ws_size,
                              hipStream_t stream) {
    const float* x    = (const float*)d_in[0];
    const int*   esrc = (const int*)d_in[1];
    const int*   edst = (const int*)d_in[2];
    const float* gi   = (const float*)d_in[3];
    const float* W1   = (const float*)d_in[4];
    const float* b1   = (const float*)d_in[5];
    const float* sW1  = (const float*)d_in[6];
    const float* sb1  = (const float*)d_in[7];
    const float* W2   = (const float*)d_in[8];
    const float* b2   = (const float*)d_in[9];
    const float* sW2  = (const float*)d_in[10];
    const float* sb2  = (const float*)d_in[11];
    const float* l1W  = (const float*)d_in[12];
    const float* l1b  = (const float*)d_in[13];
    const float* l2W  = (const float*)d_in[14];
    const float* l2b  = (const float*)d_in[15];
    const float* l3W  = (const float*)d_in[16];
    const float* l3b  = (const float*)d_in[17];
    float* out = (float*)d_out;

    char* p = (char*)d_ws;
    auto alloc = [&](size_t bytes) {
        char* r = p;
        p += (bytes + 255) & ~size_t(255);
        return (void*)r;
    };
    float* deg1  = (float*)alloc(NODES * 4);
    float* dinv1 = (float*)alloc(NODES * 4);
    float* u1    = (float*)alloc(NODES * 4);   // t -> u in place
    float* s01   = (float*)alloc(NODES * 4);
    float* sc1   = (float*)alloc(NODES * 4);
    int*   nmap1 = (int*)alloc(NODES * 4);
    int*   perm1 = (int*)alloc(N1 * 4);
    float* hp1   = (float*)alloc((size_t)N1 * HID * 4);
    int*   src2  = (int*)alloc((size_t)ECAP * 4);
    int*   dst2  = (int*)alloc((size_t)ECAP * 4);
    int*   ecnt  = (int*)alloc(4);
    float* deg2  = (float*)alloc(N1 * 4);
    float* dinv2 = (float*)alloc(N1 * 4);
    float* s02   = (float*)alloc(N1 * 4);
    float* sc2   = (float*)alloc(N1 * 4);
    int*   perm2 = (int*)alloc(N2 * 4);
    float* hw    = (float*)alloc((size_t)N1 * HID * 4);
    float* agg2  = (float*)alloc((size_t)N1 * HID * 4);
    float* x1b   = (float*)alloc(NB * 256 * 4);
    float* x2b   = (float*)alloc(NB * 256 * 4);

    hipMemsetAsync(deg1, 0, NODES * 4, stream);
    hipMemsetAsync(u1, 0, NODES * 4, stream);
    hipMemsetAsync(nmap1, 0xFF, NODES * 4, stream);
    hipMemsetAsync(ecnt, 0, 4, stream);
    hipMemsetAsync(deg2, 0, N1 * 4, stream);

    const int EB = NEDGE / 256; // 4096

    // stage 1
    k_deg<<<EB, 256, 0, stream>>>(edst, deg1, NEDGE);
    k_dinv<<<NODES / 256, 256, 0, stream>>>(deg1, dinv1, NODES);
    k_tagg<<<EB, 256, 0, stream>>>(esrc, edst, dinv1, x, u1, NEDGE);
    k_node1<<<NODES / 256, 256, 0, stream>>>(x, deg1, u1, W1, b1, sW1, sb1, s01, sc1, NODES);
    k_sagg<<<EB, 256, 0, stream>>>(esrc, edst, dinv1, s01, sc1, NEDGE);
    k_topk<NPERG, K1V, 1024><<<NB, 1024, 0, stream>>>(sc1, perm1, nmap1);
    k_hpool1<<<(N1 * HID) / 256, 256, 0, stream>>>(perm1, u1, sc1, W1, b1, hp1);
    k_readout<<<NB, HID, 0, stream>>>(hp1, x1b, K1V);
    k_compact<<<EB, 256, 0, stream>>>(esrc, edst, nmap1, src2, dst2, ecnt, NEDGE);

    // stage 2
    k_deg2<<<512, 256, 0, stream>>>(dst2, ecnt, deg2);
    k_dinv<<<N1 / 256, 256, 0, stream>>>(deg2, dinv2, N1);
    k_matmul<<<N1 / MM_ROWS, 256, 0, stream>>>(hp1, W2, hw);
    k_agginit<<<(N1 * HID) / 256, 256, 0, stream>>>(hw, deg2, agg2);
    k_eagg<<<2048, 256, 0, stream>>>(src2, dst2, ecnt, dinv2, hw, agg2);
    k_bias_relu<<<(N1 * HID) / 256, 256, 0, stream>>>(agg2, b2);
    k_score2<<<N1 / 4, 256, 0, stream>>>(agg2, sW2, sb2, deg2, s02, sc2);
    k_sagg2<<<512, 256, 0, stream>>>(src2, dst2, ecnt, dinv2, s02, sc2);
    k_topk<K1V, K2V, 256><<<NB, 256, 0, stream>>>(sc2, perm2, nullptr);
    k_read2<<<NB, HID, 0, stream>>>(agg2, sc2, perm2, x2b);

    // head
    k_head<<<NB, 128, 0, stream>>>(x1b, x2b, gi, l1W, l1b, l2W, l2b, l3W, l3b, out);
}

// Round 3
// 185.873 us; speedup vs baseline: 3.4700x; 3.4700x over previous
//
#include <hip/hip_runtime.h>
#include <math.h>

#define NB    64
#define NPG   2048      // nodes per graph
#define EPG   16384     // edges per graph
#define HID   128
#define K1V   512
#define K2V   128
#define N1    32768     // NB*K1V
#define SCAP  2048      // per-graph surviving-edge capacity (E[cnt]=1024, sigma~31)

static __device__ __forceinline__ float frelu(float v) { return v > 0.f ? v : 0.f; }

// ============ STAGE 1: one block per graph, everything in LDS ============
__global__ __launch_bounds__(1024) void k_stage1(
    const float* __restrict__ x, const int* __restrict__ esrc, const int* __restrict__ edst,
    const float* __restrict__ W1, const float* __restrict__ b1,
    const float* __restrict__ sW1, const float* __restrict__ sb1,
    float* __restrict__ ulist, float* __restrict__ tg1, float* __restrict__ x1b,
    int* __restrict__ srcs2, int* __restrict__ rs2, int* __restrict__ ic2,
    float* __restrict__ dfull2, float* __restrict__ dinv2)
{
    __shared__ float lx[NPG];     // x -> (after node phase) raw score accum
    __shared__ int   ldi[NPG];    // deg -> (after select) nmap
    __shared__ float lt[NPG];     // t accum -> u
    __shared__ float ls[NPG];     // ds01 -> tanh gates (first 512)
    __shared__ float lsc[NPG];    // dx -> sc_init -> readout sum partials
    __shared__ float sv[NPG];     // dinv -> score (sorted) -> readout max partials
    __shared__ int   si[NPG];
    __shared__ int   elist[SCAP];
    __shared__ int   ldeg[K1V];
    __shared__ int   loff[K1V];
    __shared__ float lw[HID], lbb[HID], lsw[HID];
    __shared__ int   ecur;

    const int b = blockIdx.x, tid = threadIdx.x;
    const int bn = b * NPG;
    const int be = b * EPG;

    // load x, zero accumulators
    for (int i = tid; i < NPG; i += 1024) { lx[i] = x[bn + i]; ldi[i] = 0; lt[i] = 0.f; }
    if (tid < HID) { lw[tid] = W1[tid]; lbb[tid] = b1[tid]; lsw[tid] = sW1[tid]; }
    __syncthreads();

    // deg sweep (dst only)
    for (int e = tid; e < EPG; e += 1024) atomicAdd(&ldi[edst[be + e] & (NPG - 1)], 1);
    __syncthreads();

    // dinv + dx
    for (int i = tid; i < NPG; i += 1024) {
        float df = (float)ldi[i] + 1.0f;
        float di = rsqrtf(df);
        sv[i] = di;
        lsc[i] = di * lx[i];
    }
    __syncthreads();

    // t aggregation: t[d] += dinv[s]*x[s]
    for (int e = tid; e < EPG; e += 1024) {
        int s = esrc[be + e] & (NPG - 1), d = edst[be + e] & (NPG - 1);
        atomicAdd(&lt[d], lsc[s]);
    }
    __syncthreads();

    // node phase: u, s01, ds01, sc_init; zero lx for score accumulation
    const float sb1v = sb1[0];
    for (int i = tid; i < NPG; i += 1024) {
        float df = (float)ldi[i] + 1.0f;
        float di = sv[i];
        float u = lt[i] * di + lx[i] / df;
        lt[i] = u;
        float s = 0.f;
        #pragma unroll 8
        for (int c = 0; c < HID; c++) s += frelu(fmaf(lw[c], u, lbb[c])) * lsw[c];
        ls[i] = di * s;
        lsc[i] = s / df + sb1v;
        lx[i] = 0.f;
    }
    __syncthreads();

    // score aggregation: raw[d] += ds01[s]
    for (int e = tid; e < EPG; e += 1024) {
        int s = esrc[be + e] & (NPG - 1), d = edst[be + e] & (NPG - 1);
        atomicAdd(&lx[d], ls[s]);
    }
    __syncthreads();

    // final score = sc_init + dinv*raw
    for (int i = tid; i < NPG; i += 1024) { sv[i] = lsc[i] + sv[i] * lx[i]; si[i] = i; }
    __syncthreads();

    // bitonic sort desc (tie -> lower index), 2048 elems, 1024 threads
    for (int k = 2; k <= NPG; k <<= 1) {
        for (int j = k >> 1; j > 0; j >>= 1) {
            int i = ((tid & ~(j - 1)) << 1) | (tid & (j - 1));
            int p = i | j;
            bool desc = ((i & k) == 0);
            float va = sv[i], vb = sv[p];
            int ia = si[i], ib = si[p];
            bool before = (va > vb) || (va == vb && ia < ib);
            if (before != desc) { sv[i] = vb; sv[p] = va; si[i] = ib; si[p] = ia; }
            __syncthreads();
        }
    }

    // select top-512: emit u-list + tanh gates; build nmap in ldi
    for (int i = tid; i < NPG; i += 1024) ldi[i] = -1;
    __syncthreads();
    if (tid < K1V) {
        int sl = si[tid];
        ulist[b * K1V + tid] = lt[sl];
        float g = tanhf(sv[tid]);
        ls[tid] = g;
        tg1[b * K1V + tid] = g;
        ldi[sl] = tid;
    }
    __syncthreads();

    // readout1: max/mean over 512 selected rows of relu(W1*u+b1)*gate
    {
        int grp = tid >> 7, c = tid & 127;
        float w = lw[c], bb = lbb[c];
        float mx = -INFINITY, sm = 0.f;
        for (int j = grp; j < K1V; j += 8) {
            float v = frelu(fmaf(w, lt[si[j]], bb)) * ls[j];
            mx = fmaxf(mx, v); sm += v;
        }
        sv[tid] = mx; lsc[tid] = sm;   // sv/lsc free now
        __syncthreads();
        if (tid < HID) {
            float m2 = -INFINITY, s2 = 0.f;
            for (int g2 = 0; g2 < 8; g2++) {
                m2 = fmaxf(m2, sv[g2 * 128 + tid]);
                s2 += lsc[g2 * 128 + tid];
            }
            x1b[b * 2 * HID + tid] = m2;
            x1b[b * 2 * HID + HID + tid] = s2 / (float)K1V;
        }
    }

    // edge compaction into LDS list + per-new-dst degree count
    if (tid < K1V) ldeg[tid] = 0;
    if (tid == 0) ecur = 0;
    __syncthreads();
    for (int e = tid; e < EPG; e += 1024) {
        int s2 = ldi[esrc[be + e] & (NPG - 1)];
        int d2 = ldi[edst[be + e] & (NPG - 1)];
        if (s2 >= 0 && d2 >= 0) {
            int p = atomicAdd(&ecur, 1);
            if (p < SCAP) {
                elist[p] = s2 | (d2 << 16);
                atomicAdd(&ldeg[d2], 1);
            }
        }
    }
    __syncthreads();
    int cnt = ecur < SCAP ? ecur : SCAP;

    // inclusive scan of ldeg -> loff (Hillis-Steele, 512)
    for (int i = tid; i < K1V; i += 1024) loff[i] = ldeg[i];
    __syncthreads();
    for (int off = 1; off < K1V; off <<= 1) {
        int v = 0;
        if (tid < K1V && tid >= off) v = loff[tid - off];
        __syncthreads();
        if (tid < K1V) loff[tid] += v;
        __syncthreads();
    }

    // write per-node CSR meta; convert loff to exclusive cursors
    if (tid < K1V) {
        int dg = ldeg[tid];
        int excl = loff[tid] - dg;
        int n = b * K1V + tid;
        rs2[n] = b * SCAP + excl;
        ic2[n] = dg;
        float df = (float)dg + 1.0f;
        dfull2[n] = df;
        dinv2[n] = rsqrtf(df);
        loff[tid] = excl;
    }
    __syncthreads();

    // place edges: srcs2 sorted by destination (CSR)
    for (int p = tid; p < cnt; p += 1024) {
        int pk = elist[p];
        int s2 = pk & 0xffff, d2 = pk >> 16;
        int pos = atomicAdd(&loff[d2], 1);
        srcs2[b * SCAP + pos] = b * K1V + s2;
    }
}

// ============ hw = hp @ W2, hp recomputed from (ulist, tg1) ============
#define MM_ROWS 32
__global__ __launch_bounds__(256) void k_matmul(
    const float* __restrict__ ulist, const float* __restrict__ tg1,
    const float* __restrict__ W1, const float* __restrict__ b1,
    const float* __restrict__ W2, float* __restrict__ hw)
{
    __shared__ float lh[MM_ROWS * HID];
    __shared__ float lu[MM_ROWS], lg[MM_ROWS];
    __shared__ float lw1[HID], lb1[HID];
    int row0 = blockIdx.x * MM_ROWS, tid = threadIdx.x;
    if (tid < MM_ROWS) { lu[tid] = ulist[row0 + tid]; lg[tid] = tg1[row0 + tid]; }
    if (tid < HID) { lw1[tid] = W1[tid]; lb1[tid] = b1[tid]; }
    __syncthreads();
    for (int idx = tid; idx < MM_ROWS * HID; idx += 256) {
        int j = idx >> 7, c = idx & 127;
        lh[idx] = frelu(fmaf(lw1[c], lu[j], lb1[c])) * lg[j];
    }
    __syncthreads();
    int c = tid & 127, half = tid >> 7;
    float acc[16];
    #pragma unroll
    for (int r = 0; r < 16; r++) acc[r] = 0.f;
    for (int k = 0; k < HID; k++) {
        float w = W2[k * HID + c];
        #pragma unroll
        for (int r = 0; r < 16; r++) acc[r] = fmaf(lh[(half * 16 + r) * HID + k], w, acc[r]);
    }
    #pragma unroll
    for (int r = 0; r < 16; r++) hw[(size_t)(row0 + half * 16 + r) * HID + c] = acc[r];
}

// ====== stage-2 GCN via CSR pull (no atomics), fused bias/relu/score ======
__global__ __launch_bounds__(256) void k_pull2(
    const int* __restrict__ srcs2, const int* __restrict__ rs2, const int* __restrict__ ic2,
    const float* __restrict__ dfull2, const float* __restrict__ dinv2,
    const float* __restrict__ hw, const float* __restrict__ b2,
    const float* __restrict__ sW2, const float* __restrict__ sb2,
    float* __restrict__ h2, float* __restrict__ ds02, float* __restrict__ sc2i)
{
    int node = blockIdx.x * 4 + (threadIdx.x >> 6);
    int lane = threadIdx.x & 63;
    int rs = rs2[node], cnt = ic2[node];
    float a0 = 0.f, a1 = 0.f;
    for (int j = 0; j < cnt; j++) {
        int s = srcs2[rs + j];
        float w = dinv2[s];
        a0 = fmaf(w, hw[(size_t)s * HID + lane], a0);
        a1 = fmaf(w, hw[(size_t)s * HID + 64 + lane], a1);
    }
    float df = dfull2[node], di = dinv2[node];
    float h0 = frelu(a0 * di + hw[(size_t)node * HID + lane] / df + b2[lane]);
    float h1 = frelu(a1 * di + hw[(size_t)node * HID + 64 + lane] / df + b2[lane + 64]);
    h2[(size_t)node * HID + lane] = h0;
    h2[(size_t)node * HID + 64 + lane] = h1;
    float dot = h0 * sW2[lane] + h1 * sW2[lane + 64];
    #pragma unroll
    for (int o = 32; o > 0; o >>= 1) dot += __shfl_down(dot, o);
    if (lane == 0) {
        ds02[node] = di * dot;
        sc2i[node] = dot / df + sb2[0];
    }
}

// ====== stage-2 topk (score finalize via CSR pull) + pooled readout ======
__global__ __launch_bounds__(256) void k_topk2c(
    const int* __restrict__ srcs2, const int* __restrict__ rs2, const int* __restrict__ ic2,
    const float* __restrict__ dinv2, const float* __restrict__ ds02,
    const float* __restrict__ sc2i, const float* __restrict__ h2,
    float* __restrict__ x2b)
{
    __shared__ float sv[K1V];
    __shared__ int   si[K1V];
    __shared__ int   pi[K2V];
    __shared__ float tl[K2V];
    __shared__ float rmx[HID], rsm[HID];
    const int b = blockIdx.x, tid = threadIdx.x;

    for (int r = tid; r < K1V; r += 256) {
        int n = b * K1V + r;
        int rs = rs2[n], cnt = ic2[n];
        float acc = 0.f;
        for (int j = 0; j < cnt; j++) acc += ds02[srcs2[rs + j]];
        sv[r] = sc2i[n] + dinv2[n] * acc;
        si[r] = r;
    }
    __syncthreads();
    for (int k = 2; k <= K1V; k <<= 1) {
        for (int j = k >> 1; j > 0; j >>= 1) {
            int i = ((tid & ~(j - 1)) << 1) | (tid & (j - 1));
            int p = i | j;
            bool desc = ((i & k) == 0);
            float va = sv[i], vb = sv[p];
            int ia = si[i], ib = si[p];
            bool before = (va > vb) || (va == vb && ia < ib);
            if (before != desc) { sv[i] = vb; sv[p] = va; si[i] = ib; si[p] = ia; }
            __syncthreads();
        }
    }
    if (tid < K2V) {
        pi[tid] = b * K1V + si[tid];
        tl[tid] = tanhf(sv[tid]);
    }
    __syncthreads();
    int c = tid & 127, h = tid >> 7;
    float mx = -INFINITY, sm = 0.f;
    for (int j = h; j < K2V; j += 2) {
        float v = h2[(size_t)pi[j] * HID + c] * tl[j];
        mx = fmaxf(mx, v); sm += v;
    }
    if (h == 1) { rmx[c] = mx; rsm[c] = sm; }
    __syncthreads();
    if (h == 0) {
        mx = fmaxf(mx, rmx[c]); sm += rsm[c];
        x2b[b * 2 * HID + c] = mx;
        x2b[b * 2 * HID + HID + c] = sm / (float)K2V;
    }
}

// ============ head MLP + log_softmax ============
__global__ __launch_bounds__(128) void k_head(
    const float* __restrict__ x1, const float* __restrict__ x2,
    const float* __restrict__ gi,
    const float* __restrict__ l1W, const float* __restrict__ l1b,
    const float* __restrict__ l2W, const float* __restrict__ l2b,
    const float* __restrict__ l3W, const float* __restrict__ l3b,
    float* __restrict__ out)
{
    __shared__ float z[266], z1[HID], z2[64], z3[32], red[2];
    int b = blockIdx.x, t = threadIdx.x;
    for (int i = t; i < 256; i += 128) z[i] = x1[b * 256 + i] + x2[b * 256 + i];
    if (t < 10) z[256 + t] = gi[b * 10 + t];
    __syncthreads();
    float acc = l1b[t];
    for (int k = 0; k < 266; k++) acc = fmaf(z[k], l1W[k * 128 + t], acc);
    z1[t] = frelu(acc);
    __syncthreads();
    if (t < 64) {
        float a2 = l2b[t];
        for (int k = 0; k < 128; k++) a2 = fmaf(z1[k], l2W[k * 64 + t], a2);
        z2[t] = frelu(a2);
    }
    __syncthreads();
    if (t < 32) {
        float a3 = l3b[t];
        for (int k = 0; k < 64; k++) a3 = fmaf(z2[k], l3W[k * 32 + t], a3);
        z3[t] = a3;
    }
    __syncthreads();
    if (t == 0) {
        float m = -INFINITY;
        for (int c = 0; c < 32; c++) m = fmaxf(m, z3[c]);
        float s = 0.f;
        for (int c = 0; c < 32; c++) s += expf(z3[c] - m);
        red[0] = m; red[1] = logf(s);
    }
    __syncthreads();
    if (t < 32) out[b * 32 + t] = z3[t] - red[0] - red[1];
}

// ============ launch ============
extern "C" void kernel_launch(void* const* d_in, const int* in_sizes, int n_in,
                              void* d_out, int out_size, void* d_ws, size_t ws_size,
                              hipStream_t stream) {
    const float* x    = (const float*)d_in[0];
    const int*   esrc = (const int*)d_in[1];
    const int*   edst = (const int*)d_in[2];
    const float* gi   = (const float*)d_in[3];
    const float* W1   = (const float*)d_in[4];
    const float* b1   = (const float*)d_in[5];
    const float* sW1  = (const float*)d_in[6];
    const float* sb1  = (const float*)d_in[7];
    const float* W2   = (const float*)d_in[8];
    const float* b2   = (const float*)d_in[9];
    const float* sW2  = (const float*)d_in[10];
    const float* sb2  = (const float*)d_in[11];
    const float* l1W  = (const float*)d_in[12];
    const float* l1b  = (const float*)d_in[13];
    const float* l2W  = (const float*)d_in[14];
    const float* l2b  = (const float*)d_in[15];
    const float* l3W  = (const float*)d_in[16];
    const float* l3b  = (const float*)d_in[17];
    float* out = (float*)d_out;

    char* p = (char*)d_ws;
    auto alloc = [&](size_t bytes) {
        char* r = p;
        p += (bytes + 255) & ~size_t(255);
        return (void*)r;
    };
    float* ulist  = (float*)alloc((size_t)N1 * 4);
    float* tg1    = (float*)alloc((size_t)N1 * 4);
    float* x1b    = (float*)alloc((size_t)NB * 256 * 4);
    float* x2b    = (float*)alloc((size_t)NB * 256 * 4);
    int*   srcs2  = (int*)alloc((size_t)NB * SCAP * 4);
    int*   rs2    = (int*)alloc((size_t)N1 * 4);
    int*   ic2    = (int*)alloc((size_t)N1 * 4);
    float* dfull2 = (float*)alloc((size_t)N1 * 4);
    float* dinv2  = (float*)alloc((size_t)N1 * 4);
    float* hw     = (float*)alloc((size_t)N1 * HID * 4);
    float* h2     = (float*)alloc((size_t)N1 * HID * 4);
    float* ds02   = (float*)alloc((size_t)N1 * 4);
    float* sc2i   = (float*)alloc((size_t)N1 * 4);

    k_stage1<<<NB, 1024, 0, stream>>>(x, esrc, edst, W1, b1, sW1, sb1,
                                      ulist, tg1, x1b, srcs2, rs2, ic2, dfull2, dinv2);
    k_matmul<<<N1 / MM_ROWS, 256, 0, stream>>>(ulist, tg1, W1, b1, W2, hw);
    k_pull2<<<N1 / 4, 256, 0, stream>>>(srcs2, rs2, ic2, dfull2, dinv2, hw,
                                        b2, sW2, sb2, h2, ds02, sc2i);
    k_topk2c<<<NB, 256, 0, stream>>>(srcs2, rs2, ic2, dinv2, ds02, sc2i, h2, x2b);
    k_head<<<NB, 128, 0, stream>>>(x1b, x2b, gi, l1W, l1b, l2W, l2b, l3W, l3b, out);
}

// Round 4
// 161.804 us; speedup vs baseline: 3.9862x; 1.1488x over previous
//
#include <hip/hip_runtime.h>
#include <math.h>

#define NB    64
#define NPG   2048      // nodes per graph
#define EPG   16384     // edges per graph
#define HID   128
#define K1V   512
#define K2V   128
#define N1    32768     // NB*K1V
#define SCAP  2048      // per-graph surviving-edge capacity (E[cnt]=1024)
#define MSK   (NPG - 1)

typedef unsigned int u32;

static __device__ __forceinline__ float frelu(float v) { return v > 0.f ? v : 0.f; }

// monotone float -> uint key (larger float => larger key)
static __device__ __forceinline__ u32 f2key(float f) {
    u32 u = __float_as_uint(f);
    return u ^ ((u >> 31) ? 0xFFFFFFFFu : 0x80000000u);
}

// Radix-select the K-th largest key among N LDS keys.
// Returns tau (exact 32-bit key of the K-th largest) and R = how many ==tau to keep.
template <int N, int T>
static __device__ __forceinline__ void radix_top(const u32* __restrict__ key, int K,
                                                 u32* hist, u32* misc,
                                                 u32& tau, int& R) {
    const int tid = threadIdx.x;
    if (tid == 0) { misc[0] = 0u; misc[1] = (u32)K; }
    __syncthreads();
    #pragma unroll
    for (int p = 0; p < 4; p++) {
        const int shift = 24 - 8 * p;
        for (int i = tid; i < 256; i += T) hist[i] = 0u;
        __syncthreads();
        const u32 prefix = misc[0];
        const u32 need   = misc[1];
        for (int i = tid; i < N; i += T) {
            u32 k = key[i];
            bool ok = (p == 0) || ((k >> (shift + 8)) == prefix);
            if (ok) atomicAdd(&hist[(k >> shift) & 255u], 1u);
        }
        __syncthreads();
        if (tid < 64) {
            const int lane = tid;
            u32 c0 = hist[4 * lane + 0], c1 = hist[4 * lane + 1];
            u32 c2 = hist[4 * lane + 2], c3 = hist[4 * lane + 3];
            u32 local = c0 + c1 + c2 + c3;
            u32 inc = local;
            #pragma unroll
            for (int off = 1; off < 64; off <<= 1) {
                u32 v = __shfl_down(inc, off);
                if (lane + off < 64) inc += v;
            }
            u32 excl = inc - local;                 // count in bins above this lane's 4
            u32 ge3 = excl + c3, ge2 = ge3 + c2, ge1 = ge2 + c1, ge0 = ge1 + c0;
            int selb = -1; u32 gt = 0;
            if      (ge3 >= need && excl < need) { selb = 4 * lane + 3; gt = excl; }
            else if (ge2 >= need && ge3  < need) { selb = 4 * lane + 2; gt = ge3; }
            else if (ge1 >= need && ge2  < need) { selb = 4 * lane + 1; gt = ge2; }
            else if (ge0 >= need && ge1  < need) { selb = 4 * lane + 0; gt = ge1; }
            if (selb >= 0) { misc[0] = (prefix << 8) | (u32)selb; misc[1] = need - gt; }
        }
        __syncthreads();
    }
    tau = misc[0];
    R = (int)misc[1];
}

// ============ STAGE 1: one block per graph, everything in LDS ============
__global__ __launch_bounds__(1024) void k_stage1(
    const float* __restrict__ x, const int* __restrict__ esrc, const int* __restrict__ edst,
    const float* __restrict__ W1, const float* __restrict__ b1,
    const float* __restrict__ sW1, const float* __restrict__ sb1,
    float* __restrict__ ulist, float* __restrict__ tg1, float* __restrict__ x1b,
    int* __restrict__ srcs2, int* __restrict__ rs2, int* __restrict__ ic2,
    float* __restrict__ dfull2, float* __restrict__ dinv2)
{
    __shared__ float lx[NPG];      // x -> score accum -> readout max partials
    __shared__ int   ldi[NPG];     // deg -> nmap
    __shared__ float lt[NPG];      // t accum -> u   (tail reused as ldeg cursors)
    __shared__ float ldv[NPG];     // dinv -> readout sum partials
    __shared__ float ls[NPG];      // dx -> ds01     (reused as elist)
    __shared__ float lsc[NPG];     // sc_init -> final score
    __shared__ u32   lkey[NPG];    // sortable keys
    __shared__ int   sellist[K1V];
    __shared__ float ul[K1V], tgl[K1V];
    __shared__ u32   hist[256];
    __shared__ u32   misc[2];
    __shared__ u32   wsum[16];
    __shared__ int   scnt, ecur;
    __shared__ float lw[HID], lbb[HID], lsw[HID];

    int* elist = (int*)ls;
    int* ldeg  = (int*)lt;

    const int b = blockIdx.x, tid = threadIdx.x;
    const int be = b * EPG;
    const int lane = tid & 63, wv = tid >> 6;
    const int4* s4 = (const int4*)(esrc + be);
    const int4* d4 = (const int4*)(edst + be);

    // P0: load x, zero deg/t, load weights
    for (int i = tid; i < NPG; i += 1024) { lx[i] = x[b * NPG + i]; ldi[i] = 0; lt[i] = 0.f; }
    if (tid < HID) { lw[tid] = W1[tid]; lbb[tid] = b1[tid]; lsw[tid] = sW1[tid]; }
    __syncthreads();

    // P1: deg sweep (dst only), int4
    for (int q = tid; q < EPG / 4; q += 1024) {
        int4 dd = d4[q];
        atomicAdd(&ldi[dd.x & MSK], 1); atomicAdd(&ldi[dd.y & MSK], 1);
        atomicAdd(&ldi[dd.z & MSK], 1); atomicAdd(&ldi[dd.w & MSK], 1);
    }
    __syncthreads();

    // P2: dinv + dx
    for (int i = tid; i < NPG; i += 1024) {
        float df = (float)ldi[i] + 1.0f;
        float di = rsqrtf(df);
        ldv[i] = di;
        ls[i] = di * lx[i];
    }
    __syncthreads();

    // P3: t sweep: t[d] += dx[s]
    for (int q = tid; q < EPG / 4; q += 1024) {
        int4 ss = s4[q]; int4 dd = d4[q];
        atomicAdd(&lt[dd.x & MSK], ls[ss.x & MSK]);
        atomicAdd(&lt[dd.y & MSK], ls[ss.y & MSK]);
        atomicAdd(&lt[dd.z & MSK], ls[ss.z & MSK]);
        atomicAdd(&lt[dd.w & MSK], ls[ss.w & MSK]);
    }
    __syncthreads();

    // P4: node phase: u, s01, ds01, sc_init; zero lx for score accum
    const float sb1v = sb1[0];
    for (int i = tid; i < NPG; i += 1024) {
        float df = (float)ldi[i] + 1.0f;
        float di = ldv[i];
        float u = lt[i] * di + lx[i] / df;
        lt[i] = u;
        float s = 0.f;
        #pragma unroll 8
        for (int c = 0; c < HID; c++) s += frelu(fmaf(lw[c], u, lbb[c])) * lsw[c];
        ls[i] = di * s;
        lsc[i] = s / df + sb1v;
        lx[i] = 0.f;
    }
    __syncthreads();

    // P5: score sweep: raw[d] += ds01[s]
    for (int q = tid; q < EPG / 4; q += 1024) {
        int4 ss = s4[q]; int4 dd = d4[q];
        atomicAdd(&lx[dd.x & MSK], ls[ss.x & MSK]);
        atomicAdd(&lx[dd.y & MSK], ls[ss.y & MSK]);
        atomicAdd(&lx[dd.z & MSK], ls[ss.z & MSK]);
        atomicAdd(&lx[dd.w & MSK], ls[ss.w & MSK]);
    }
    __syncthreads();

    // P6: final score + keys
    for (int i = tid; i < NPG; i += 1024) {
        float sc = lsc[i] + ldv[i] * lx[i];
        lsc[i] = sc;
        lkey[i] = f2key(sc);
    }
    if (tid == 0) { scnt = 0; ecur = 0; }
    __syncthreads();

    // P7: radix select top-K1V
    u32 tau; int R;
    radix_top<NPG, 1024>(lkey, K1V, hist, misc, tau, R);

    // P8: stable tie rank (lowest index first) + build selected list
    {
        int e0 = tid * 2, e1 = e0 + 1;
        u32 k0 = lkey[e0], k1 = lkey[e1];
        int q0 = (k0 == tau) ? 1 : 0, q1 = (k1 == tau) ? 1 : 0;
        u32 pairv = (u32)(q0 + q1);
        u32 inc = pairv;
        #pragma unroll
        for (int off = 1; off < 64; off <<= 1) {
            u32 v = __shfl_up(inc, off);
            if (lane >= off) inc += v;
        }
        if (lane == 63) wsum[wv] = inc;
        __syncthreads();
        if (tid == 0) { u32 run = 0; for (int w2 = 0; w2 < 16; w2++) { u32 v = wsum[w2]; wsum[w2] = run; run += v; } }
        __syncthreads();
        u32 base = wsum[wv] + inc - pairv;      // exclusive tie-rank before e0
        bool sel0 = (k0 > tau) || (q0 && base < (u32)R);
        bool sel1 = (k1 > tau) || (q1 && (base + (u32)q0) < (u32)R);
        if (sel0) { int pos = atomicAdd(&scnt, 1); sellist[pos] = e0; }
        if (sel1) { int pos = atomicAdd(&scnt, 1); sellist[pos] = e1; }
        __syncthreads();
    }

    // P9: nmap + emit u/gate
    for (int i = tid; i < NPG; i += 1024) ldi[i] = -1;
    __syncthreads();
    if (tid < K1V) {
        int node = sellist[tid];
        float uu = lt[node];
        float g = tanhf(lsc[node]);
        ul[tid] = uu; tgl[tid] = g;
        ulist[b * K1V + tid] = uu; tg1[b * K1V + tid] = g;
        ldi[node] = tid;
    }
    __syncthreads();

    // P10: readout1 (max/mean over 512 rows of relu(W1*u+b1)*gate)
    {
        int grp = tid >> 7, c = tid & 127;
        float w = lw[c], bb = lbb[c];
        float mx = -INFINITY, sm = 0.f;
        for (int j = grp; j < K1V; j += 8) {
            float v = frelu(fmaf(w, ul[j], bb)) * tgl[j];
            mx = fmaxf(mx, v); sm += v;
        }
        lx[tid] = mx; ldv[tid] = sm;
        if (tid >= 512) ldeg[tid - 512] = 0;   // init CSR degree counters (overlay on lt)
        __syncthreads();
        if (tid < HID) {
            float m2 = -INFINITY, s2 = 0.f;
            #pragma unroll
            for (int g2 = 0; g2 < 8; g2++) {
                m2 = fmaxf(m2, lx[g2 * 128 + tid]);
                s2 += ldv[g2 * 128 + tid];
            }
            x1b[b * 2 * HID + tid] = m2;
            x1b[b * 2 * HID + HID + tid] = s2 / (float)K1V;
        }
    }
    __syncthreads();

    // P11: edge compaction (elist overlays ls)
    for (int q = tid; q < EPG / 4; q += 1024) {
        int4 ss = s4[q]; int4 dd = d4[q];
        int sa[4] = { ss.x & MSK, ss.y & MSK, ss.z & MSK, ss.w & MSK };
        int da[4] = { dd.x & MSK, dd.y & MSK, dd.z & MSK, dd.w & MSK };
        #pragma unroll
        for (int r = 0; r < 4; r++) {
            int s2 = ldi[sa[r]], d2 = ldi[da[r]];
            if (s2 >= 0 && d2 >= 0) {
                int p = atomicAdd(&ecur, 1);
                if (p < SCAP) { elist[p] = s2 | (d2 << 16); atomicAdd(&ldeg[d2], 1); }
            }
        }
    }
    __syncthreads();
    int cnt = ecur < SCAP ? ecur : SCAP;

    // P12: exclusive scan of ldeg (512) via wave shuffles; write CSR meta
    {
        int dv = 0; u32 inc2 = 0;
        if (tid < K1V) { dv = ldeg[tid]; inc2 = (u32)dv; }
        #pragma unroll
        for (int off = 1; off < 64; off <<= 1) {
            u32 v = __shfl_up(inc2, off);
            if (lane >= off) inc2 += v;
        }
        if (tid < K1V && lane == 63) wsum[wv] = inc2;
        __syncthreads();
        if (tid == 0) { u32 run = 0; for (int w2 = 0; w2 < 8; w2++) { u32 v = wsum[w2]; wsum[w2] = run; run += v; } }
        __syncthreads();
        if (tid < K1V) {
            u32 excl = wsum[wv] + inc2 - (u32)dv;
            int n = b * K1V + tid;
            rs2[n] = b * SCAP + (int)excl;
            ic2[n] = dv;
            float df = (float)dv + 1.0f;
            dfull2[n] = df;
            dinv2[n] = rsqrtf(df);
            ldeg[tid] = (int)excl;   // becomes cursor
        }
        __syncthreads();
    }

    // P13: place edges into CSR
    for (int p = tid; p < cnt; p += 1024) {
        int pk = elist[p];
        int s2 = pk & 0xffff, d2 = pk >> 16;
        int pos = atomicAdd(&ldeg[d2], 1);
        srcs2[b * SCAP + pos] = b * K1V + s2;
    }
}

// ============ hw = hp @ W2, hp recomputed from (ulist, tg1) ============
#define MM_ROWS 32
__global__ __launch_bounds__(256) void k_matmul(
    const float* __restrict__ ulist, const float* __restrict__ tg1,
    const float* __restrict__ W1, const float* __restrict__ b1,
    const float* __restrict__ W2, float* __restrict__ hw)
{
    __shared__ float lh[MM_ROWS * HID];
    __shared__ float lu[MM_ROWS], lg[MM_ROWS];
    __shared__ float lw1[HID], lb1[HID];
    int row0 = blockIdx.x * MM_ROWS, tid = threadIdx.x;
    if (tid < MM_ROWS) { lu[tid] = ulist[row0 + tid]; lg[tid] = tg1[row0 + tid]; }
    if (tid < HID) { lw1[tid] = W1[tid]; lb1[tid] = b1[tid]; }
    __syncthreads();
    for (int idx = tid; idx < MM_ROWS * HID; idx += 256) {
        int j = idx >> 7, c = idx & 127;
        lh[idx] = frelu(fmaf(lw1[c], lu[j], lb1[c])) * lg[j];
    }
    __syncthreads();
    int c = tid & 127, half = tid >> 7;
    float acc[16];
    #pragma unroll
    for (int r = 0; r < 16; r++) acc[r] = 0.f;
    for (int k = 0; k < HID; k++) {
        float w = W2[k * HID + c];
        #pragma unroll
        for (int r = 0; r < 16; r++) acc[r] = fmaf(lh[(half * 16 + r) * HID + k], w, acc[r]);
    }
    #pragma unroll
    for (int r = 0; r < 16; r++) hw[(size_t)(row0 + half * 16 + r) * HID + c] = acc[r];
}

// ====== stage-2 GCN via CSR pull (no atomics), fused bias/relu/score ======
__global__ __launch_bounds__(256) void k_pull2(
    const int* __restrict__ srcs2, const int* __restrict__ rs2, const int* __restrict__ ic2,
    const float* __restrict__ dfull2, const float* __restrict__ dinv2,
    const float* __restrict__ hw, const float* __restrict__ b2,
    const float* __restrict__ sW2, const float* __restrict__ sb2,
    float* __restrict__ h2, float* __restrict__ ds02, float* __restrict__ sc2i)
{
    int node = blockIdx.x * 4 + (threadIdx.x >> 6);
    int lane = threadIdx.x & 63;
    int rs = rs2[node], cnt = ic2[node];
    float a0 = 0.f, a1 = 0.f;
    for (int j = 0; j < cnt; j++) {
        int s = srcs2[rs + j];
        float w = dinv2[s];
        a0 = fmaf(w, hw[(size_t)s * HID + lane], a0);
        a1 = fmaf(w, hw[(size_t)s * HID + 64 + lane], a1);
    }
    float df = dfull2[node], di = dinv2[node];
    float h0 = frelu(a0 * di + hw[(size_t)node * HID + lane] / df + b2[lane]);
    float h1 = frelu(a1 * di + hw[(size_t)node * HID + 64 + lane] / df + b2[lane + 64]);
    h2[(size_t)node * HID + lane] = h0;
    h2[(size_t)node * HID + 64 + lane] = h1;
    float dot = h0 * sW2[lane] + h1 * sW2[lane + 64];
    #pragma unroll
    for (int o = 32; o > 0; o >>= 1) dot += __shfl_down(dot, o);
    if (lane == 0) {
        ds02[node] = di * dot;
        sc2i[node] = dot / df + sb2[0];
    }
}

// ====== stage-2: finalize scores, radix-select top-128, pooled readout ======
__global__ __launch_bounds__(256) void k_topk2c(
    const int* __restrict__ srcs2, const int* __restrict__ rs2, const int* __restrict__ ic2,
    const float* __restrict__ dinv2, const float* __restrict__ ds02,
    const float* __restrict__ sc2i, const float* __restrict__ h2,
    float* __restrict__ x2b)
{
    __shared__ float sv[K1V];
    __shared__ u32   skey[K1V];
    __shared__ u32   hist[256];
    __shared__ u32   misc[2];
    __shared__ u32   wsum[4];
    __shared__ int   plist[K2V];
    __shared__ float tl[K2V];
    __shared__ float rmx[HID], rsm[HID];
    __shared__ int   scnt;
    const int b = blockIdx.x, tid = threadIdx.x;
    const int lane = tid & 63, wv = tid >> 6;
    if (tid == 0) scnt = 0;
    for (int r = tid; r < K1V; r += 256) {
        int n = b * K1V + r;
        int rs = rs2[n], cnt = ic2[n];
        float acc = 0.f;
        for (int j = 0; j < cnt; j++) acc += ds02[srcs2[rs + j]];
        float sc = sc2i[n] + dinv2[n] * acc;
        sv[r] = sc; skey[r] = f2key(sc);
    }
    __syncthreads();
    u32 tau; int R;
    radix_top<K1V, 256>(skey, K2V, hist, misc, tau, R);
    {
        int e0 = tid * 2, e1 = e0 + 1;
        u32 k0 = skey[e0], k1 = skey[e1];
        int q0 = (k0 == tau) ? 1 : 0, q1 = (k1 == tau) ? 1 : 0;
        u32 pairv = (u32)(q0 + q1);
        u32 inc = pairv;
        #pragma unroll
        for (int off = 1; off < 64; off <<= 1) {
            u32 v = __shfl_up(inc, off);
            if (lane >= off) inc += v;
        }
        if (lane == 63) wsum[wv] = inc;
        __syncthreads();
        if (tid == 0) { u32 run = 0; for (int w2 = 0; w2 < 4; w2++) { u32 v = wsum[w2]; wsum[w2] = run; run += v; } }
        __syncthreads();
        u32 base = wsum[wv] + inc - pairv;
        bool sel0 = (k0 > tau) || (q0 && base < (u32)R);
        bool sel1 = (k1 > tau) || (q1 && (base + (u32)q0) < (u32)R);
        if (sel0) { int pos = atomicAdd(&scnt, 1); plist[pos] = b * K1V + e0; tl[pos] = tanhf(sv[e0]); }
        if (sel1) { int pos = atomicAdd(&scnt, 1); plist[pos] = b * K1V + e1; tl[pos] = tanhf(sv[e1]); }
        __syncthreads();
    }
    int c = tid & 127, h = tid >> 7;
    float mx = -INFINITY, sm = 0.f;
    for (int j = h; j < K2V; j += 2) {
        float v = h2[(size_t)plist[j] * HID + c] * tl[j];
        mx = fmaxf(mx, v); sm += v;
    }
    if (h == 1) { rmx[c] = mx; rsm[c] = sm; }
    __syncthreads();
    if (h == 0) {
        mx = fmaxf(mx, rmx[c]); sm += rsm[c];
        x2b[b * 2 * HID + c] = mx;
        x2b[b * 2 * HID + HID + c] = sm / (float)K2V;
    }
}

// ============ head MLP + log_softmax ============
__global__ __launch_bounds__(128) void k_head(
    const float* __restrict__ x1, const float* __restrict__ x2,
    const float* __restrict__ gi,
    const float* __restrict__ l1W, const float* __restrict__ l1b,
    const float* __restrict__ l2W, const float* __restrict__ l2b,
    const float* __restrict__ l3W, const float* __restrict__ l3b,
    float* __restrict__ out)
{
    __shared__ float z[266], z1[HID], z2[64], z3[32], red[2];
    int b = blockIdx.x, t = threadIdx.x;
    for (int i = t; i < 256; i += 128) z[i] = x1[b * 256 + i] + x2[b * 256 + i];
    if (t < 10) z[256 + t] = gi[b * 10 + t];
    __syncthreads();
    float acc = l1b[t];
    for (int k = 0; k < 266; k++) acc = fmaf(z[k], l1W[k * 128 + t], acc);
    z1[t] = frelu(acc);
    __syncthreads();
    if (t < 64) {
        float a2 = l2b[t];
        for (int k = 0; k < 128; k++) a2 = fmaf(z1[k], l2W[k * 64 + t], a2);
        z2[t] = frelu(a2);
    }
    __syncthreads();
    if (t < 32) {
        float a3 = l3b[t];
        for (int k = 0; k < 64; k++) a3 = fmaf(z2[k], l3W[k * 32 + t], a3);
        z3[t] = a3;
    }
    __syncthreads();
    if (t == 0) {
        float m = -INFINITY;
        for (int c = 0; c < 32; c++) m = fmaxf(m, z3[c]);
        float s = 0.f;
        for (int c = 0; c < 32; c++) s += expf(z3[c] - m);
        red[0] = m; red[1] = logf(s);
    }
    __syncthreads();
    if (t < 32) out[b * 32 + t] = z3[t] - red[0] - red[1];
}

// ============ launch ============
extern "C" void kernel_launch(void* const* d_in, const int* in_sizes, int n_in,
                              void* d_out, int out_size, void* d_ws, size_t ws_size,
                              hipStream_t stream) {
    const float* x    = (const float*)d_in[0];
    const int*   esrc = (const int*)d_in[1];
    const int*   edst = (const int*)d_in[2];
    const float* gi   = (const float*)d_in[3];
    const float* W1   = (const float*)d_in[4];
    const float* b1   = (const float*)d_in[5];
    const float* sW1  = (const float*)d_in[6];
    const float* sb1  = (const float*)d_in[7];
    const float* W2   = (const float*)d_in[8];
    const float* b2   = (const float*)d_in[9];
    const float* sW2  = (const float*)d_in[10];
    const float* sb2  = (const float*)d_in[11];
    const float* l1W  = (const float*)d_in[12];
    const float* l1b  = (const float*)d_in[13];
    const float* l2W  = (const float*)d_in[14];
    const float* l2b  = (const float*)d_in[15];
    const float* l3W  = (const float*)d_in[16];
    const float* l3b  = (const float*)d_in[17];
    float* out = (float*)d_out;

    char* p = (char*)d_ws;
    auto alloc = [&](size_t bytes) {
        char* r = p;
        p += (bytes + 255) & ~size_t(255);
        return (void*)r;
    };
    float* ulist  = (float*)alloc((size_t)N1 * 4);
    float* tg1    = (float*)alloc((size_t)N1 * 4);
    float* x1b    = (float*)alloc((size_t)NB * 256 * 4);
    float* x2b    = (float*)alloc((size_t)NB * 256 * 4);
    int*   srcs2  = (int*)alloc((size_t)NB * SCAP * 4);
    int*   rs2    = (int*)alloc((size_t)N1 * 4);
    int*   ic2    = (int*)alloc((size_t)N1 * 4);
    float* dfull2 = (float*)alloc((size_t)N1 * 4);
    float* dinv2  = (float*)alloc((size_t)N1 * 4);
    float* hw     = (float*)alloc((size_t)N1 * HID * 4);
    float* h2     = (float*)alloc((size_t)N1 * HID * 4);
    float* ds02   = (float*)alloc((size_t)N1 * 4);
    float* sc2i   = (float*)alloc((size_t)N1 * 4);

    k_stage1<<<NB, 1024, 0, stream>>>(x, esrc, edst, W1, b1, sW1, sb1,
                                      ulist, tg1, x1b, srcs2, rs2, ic2, dfull2, dinv2);
    k_matmul<<<N1 / MM_ROWS, 256, 0, stream>>>(ulist, tg1, W1, b1, W2, hw);
    k_pull2<<<N1 / 4, 256, 0, stream>>>(srcs2, rs2, ic2, dfull2, dinv2, hw,
                                        b2, sW2, sb2, h2, ds02, sc2i);
    k_topk2c<<<NB, 256, 0, stream>>>(srcs2, rs2, ic2, dinv2, ds02, sc2i, h2, x2b);
    k_head<<<NB, 128, 0, stream>>>(x1b, x2b, gi, l1W, l1b, l2W, l2b, l3W, l3b, out);
}

// Round 5
// 145.958 us; speedup vs baseline: 4.4189x; 1.1086x over previous
//
#include <hip/hip_runtime.h>
#include <math.h>

#define NB    64
#define NPG   2048      // nodes per graph
#define EPG   16384     // edges per graph
#define HID   128
#define K1V   512
#define K2V   128
#define N1    32768     // NB*K1V
#define SCAP  2048      // per-graph surviving-edge capacity
#define MSK   (NPG - 1)
#define NQ    8         // edge segments per graph
#define ESEG  (EPG / NQ)   // 2048
#define QCAP  256       // per-segment survivor capacity (E~128, sigma~11)

typedef unsigned int u32;

static __device__ __forceinline__ float frelu(float v) { return v > 0.f ? v : 0.f; }

// monotone float -> uint key (larger float => larger key)
static __device__ __forceinline__ u32 f2key(float f) {
    u32 u = __float_as_uint(f);
    return u ^ ((u >> 31) ? 0xFFFFFFFFu : 0x80000000u);
}

// Radix-select the K-th largest key among N LDS keys.
template <int N, int T>
static __device__ __forceinline__ void radix_top(const u32* __restrict__ key, int K,
                                                 u32* hist, u32* misc,
                                                 u32& tau, int& R) {
    const int tid = threadIdx.x;
    if (tid == 0) { misc[0] = 0u; misc[1] = (u32)K; }
    __syncthreads();
    #pragma unroll
    for (int p = 0; p < 4; p++) {
        const int shift = 24 - 8 * p;
        for (int i = tid; i < 256; i += T) hist[i] = 0u;
        __syncthreads();
        const u32 prefix = misc[0];
        const u32 need   = misc[1];
        for (int i = tid; i < N; i += T) {
            u32 k = key[i];
            bool ok = (p == 0) || ((k >> (shift + 8)) == prefix);
            if (ok) atomicAdd(&hist[(k >> shift) & 255u], 1u);
        }
        __syncthreads();
        if (tid < 64) {
            const int lane = tid;
            u32 c0 = hist[4 * lane + 0], c1 = hist[4 * lane + 1];
            u32 c2 = hist[4 * lane + 2], c3 = hist[4 * lane + 3];
            u32 local = c0 + c1 + c2 + c3;
            u32 inc = local;
            #pragma unroll
            for (int off = 1; off < 64; off <<= 1) {
                u32 v = __shfl_down(inc, off);
                if (lane + off < 64) inc += v;
            }
            u32 excl = inc - local;
            u32 ge3 = excl + c3, ge2 = ge3 + c2, ge1 = ge2 + c1, ge0 = ge1 + c0;
            int selb = -1; u32 gt = 0;
            if      (ge3 >= need && excl < need) { selb = 4 * lane + 3; gt = excl; }
            else if (ge2 >= need && ge3  < need) { selb = 4 * lane + 2; gt = ge3; }
            else if (ge1 >= need && ge2  < need) { selb = 4 * lane + 1; gt = ge2; }
            else if (ge0 >= need && ge1  < need) { selb = 4 * lane + 0; gt = ge1; }
            if (selb >= 0) { misc[0] = (prefix << 8) | (u32)selb; misc[1] = need - gt; }
        }
        __syncthreads();
    }
    tau = misc[0];
    R = (int)misc[1];
}

// ===== K1: per-segment degree histogram (512 blocks = 8/graph) =====
__global__ __launch_bounds__(256) void k_deg8(const int* __restrict__ edst,
                                              int* __restrict__ degp) {
    __shared__ int cnt[NPG];
    const int bid = blockIdx.x, tid = threadIdx.x;
    const int g = bid >> 3, q = bid & 7;
    for (int i = tid; i < NPG; i += 256) cnt[i] = 0;
    __syncthreads();
    const int4* d4 = (const int4*)(edst + g * EPG + q * ESEG);
    for (int i = tid; i < ESEG / 4; i += 256) {
        int4 dd = d4[i];
        atomicAdd(&cnt[dd.x & MSK], 1); atomicAdd(&cnt[dd.y & MSK], 1);
        atomicAdd(&cnt[dd.z & MSK], 1); atomicAdd(&cnt[dd.w & MSK], 1);
    }
    __syncthreads();
    int4* op = (int4*)(degp + (size_t)bid * NPG);
    const int4* cp = (const int4*)cnt;
    for (int i = tid; i < NPG / 4; i += 256) op[i] = cp[i];
}

// ===== K2: node pass A: deg reduce -> df, dinv, dx =====
__global__ __launch_bounds__(256) void k_nodeA(const float* __restrict__ x,
                                               const int* __restrict__ degp,
                                               float* __restrict__ df_g,
                                               float* __restrict__ di_g,
                                               float* __restrict__ dx_g) {
    int i = blockIdx.x * 256 + threadIdx.x;
    int g = i >> 11, loc = i & MSK;
    int deg = 0;
    #pragma unroll
    for (int q = 0; q < NQ; q++) deg += degp[(size_t)(g * NQ + q) * NPG + loc];
    float df = (float)deg + 1.0f;
    float di = rsqrtf(df);
    df_g[i] = df; di_g[i] = di; dx_g[i] = di * x[i];
}

// ===== K3/K5: per-segment scatter-add sweep: out_partial[d] += val[s] =====
__global__ __launch_bounds__(256) void k_fsweep(const int* __restrict__ esrc,
                                                const int* __restrict__ edst,
                                                const float* __restrict__ val_g,
                                                float* __restrict__ outp) {
    __shared__ float lv[NPG];
    __shared__ float acc[NPG];
    const int bid = blockIdx.x, tid = threadIdx.x;
    const int g = bid >> 3, q = bid & 7;
    for (int i = tid; i < NPG; i += 256) { lv[i] = val_g[(size_t)g * NPG + i]; acc[i] = 0.f; }
    __syncthreads();
    const int4* s4 = (const int4*)(esrc + g * EPG + q * ESEG);
    const int4* d4 = (const int4*)(edst + g * EPG + q * ESEG);
    for (int i = tid; i < ESEG / 4; i += 256) {
        int4 ss = s4[i]; int4 dd = d4[i];
        atomicAdd(&acc[dd.x & MSK], lv[ss.x & MSK]);
        atomicAdd(&acc[dd.y & MSK], lv[ss.y & MSK]);
        atomicAdd(&acc[dd.z & MSK], lv[ss.z & MSK]);
        atomicAdd(&acc[dd.w & MSK], lv[ss.w & MSK]);
    }
    __syncthreads();
    float4* op = (float4*)(outp + (size_t)bid * NPG);
    const float4* ap = (const float4*)acc;
    for (int i = tid; i < NPG / 4; i += 256) op[i] = ap[i];
}

// ===== K4: node pass B: t reduce -> u, MLP -> ds01, sc_init =====
__global__ __launch_bounds__(256) void k_nodeB(const float* __restrict__ x,
                                               const float* __restrict__ tp,
                                               const float* __restrict__ df_g,
                                               const float* __restrict__ di_g,
                                               const float* __restrict__ W1,
                                               const float* __restrict__ b1,
                                               const float* __restrict__ sW1,
                                               const float* __restrict__ sb1,
                                               float* __restrict__ u_g,
                                               float* __restrict__ ds01_g,
                                               float* __restrict__ sci_g) {
    __shared__ float lw[HID], lbb[HID], lsw[HID];
    const int tid = threadIdx.x;
    if (tid < HID) { lw[tid] = W1[tid]; lbb[tid] = b1[tid]; lsw[tid] = sW1[tid]; }
    __syncthreads();
    int i = blockIdx.x * 256 + tid;
    int g = i >> 11, loc = i & MSK;
    float t = 0.f;
    #pragma unroll
    for (int q = 0; q < NQ; q++) t += tp[(size_t)(g * NQ + q) * NPG + loc];
    float df = df_g[i], di = di_g[i];
    float u = t * di + x[i] / df;
    float s = 0.f;
    #pragma unroll 8
    for (int c = 0; c < HID; c++) s += frelu(fmaf(lw[c], u, lbb[c])) * lsw[c];
    u_g[i] = u;
    ds01_g[i] = di * s;
    sci_g[i] = s / df + sb1[0];
}

// ===== K6: per-graph: score finalize, radix top-512, nmap, readout1 =====
__global__ __launch_bounds__(1024) void k_select(
    const float* __restrict__ sci_g, const float* __restrict__ di_g,
    const float* __restrict__ scp, const float* __restrict__ u_g,
    const float* __restrict__ W1, const float* __restrict__ b1,
    float* __restrict__ ulist, float* __restrict__ tg1, float* __restrict__ x1b,
    int* __restrict__ nmap_g)
{
    __shared__ float lsc[NPG];
    __shared__ u32   lkey[NPG];
    __shared__ int   ln[NPG];
    __shared__ float ul[K1V], tgl[K1V];
    __shared__ int   sellist[K1V];
    __shared__ u32   hist[256], misc[2], wsum[16];
    __shared__ int   scnt;
    __shared__ float lw[HID], lbb[HID];
    const int b = blockIdx.x, tid = threadIdx.x;
    const int lane = tid & 63, wv = tid >> 6;

    for (int i = tid; i < NPG; i += 1024) {
        float a = 0.f;
        #pragma unroll
        for (int q = 0; q < NQ; q++) a += scp[(size_t)(b * NQ + q) * NPG + i];
        float sc = sci_g[(size_t)b * NPG + i] + di_g[(size_t)b * NPG + i] * a;
        lsc[i] = sc;
        lkey[i] = f2key(sc);
        ln[i] = -1;
    }
    if (tid < HID) { lw[tid] = W1[tid]; lbb[tid] = b1[tid]; }
    if (tid == 0) scnt = 0;
    __syncthreads();

    u32 tau; int R;
    radix_top<NPG, 1024>(lkey, K1V, hist, misc, tau, R);

    // stable tie rank (lowest index first)
    {
        int e0 = tid * 2, e1 = e0 + 1;
        u32 k0 = lkey[e0], k1 = lkey[e1];
        int q0 = (k0 == tau) ? 1 : 0, q1 = (k1 == tau) ? 1 : 0;
        u32 pairv = (u32)(q0 + q1);
        u32 inc = pairv;
        #pragma unroll
        for (int off = 1; off < 64; off <<= 1) {
            u32 v = __shfl_up(inc, off);
            if (lane >= off) inc += v;
        }
        if (lane == 63) wsum[wv] = inc;
        __syncthreads();
        if (tid == 0) { u32 run = 0; for (int w2 = 0; w2 < 16; w2++) { u32 v = wsum[w2]; wsum[w2] = run; run += v; } }
        __syncthreads();
        u32 base = wsum[wv] + inc - pairv;
        bool sel0 = (k0 > tau) || (q0 && base < (u32)R);
        bool sel1 = (k1 > tau) || (q1 && (base + (u32)q0) < (u32)R);
        if (sel0) { int pos = atomicAdd(&scnt, 1); sellist[pos] = e0; }
        if (sel1) { int pos = atomicAdd(&scnt, 1); sellist[pos] = e1; }
        __syncthreads();
    }

    if (tid < K1V) {
        int node = sellist[tid];
        float uu = u_g[(size_t)b * NPG + node];
        float g = tanhf(lsc[node]);
        ul[tid] = uu; tgl[tid] = g;
        ulist[b * K1V + tid] = uu;
        tg1[b * K1V + tid] = g;
        ln[node] = tid;
    }
    __syncthreads();
    for (int i = tid; i < NPG; i += 1024) nmap_g[(size_t)b * NPG + i] = ln[i];

    // readout1: reuse lkey as two 1024-float partial arrays
    float* rp = (float*)lkey;
    {
        int grp = tid >> 7, c = tid & 127;
        float w = lw[c], bb = lbb[c];
        float mx = -INFINITY, sm = 0.f;
        for (int j = grp; j < K1V; j += 8) {
            float v = frelu(fmaf(w, ul[j], bb)) * tgl[j];
            mx = fmaxf(mx, v); sm += v;
        }
        __syncthreads();
        rp[tid] = mx; rp[1024 + tid] = sm;
        __syncthreads();
        if (tid < HID) {
            float m2 = -INFINITY, s2 = 0.f;
            #pragma unroll
            for (int g2 = 0; g2 < 8; g2++) {
                m2 = fmaxf(m2, rp[g2 * 128 + tid]);
                s2 += rp[1024 + g2 * 128 + tid];
            }
            x1b[b * 2 * HID + tid] = m2;
            x1b[b * 2 * HID + HID + tid] = s2 / (float)K1V;
        }
    }
}

// ===== K7: per-segment edge compaction =====
__global__ __launch_bounds__(256) void k_compact8(const int* __restrict__ esrc,
                                                  const int* __restrict__ edst,
                                                  const int* __restrict__ nmap_g,
                                                  int* __restrict__ epair,
                                                  int* __restrict__ eqcnt,
                                                  int* __restrict__ ldegp) {
    __shared__ int lnm[NPG];
    __shared__ int pbuf[QCAP];
    __shared__ int lda[K1V];
    __shared__ int lcnt;
    const int bid = blockIdx.x, tid = threadIdx.x;
    const int g = bid >> 3, q = bid & 7;
    for (int i = tid; i < NPG; i += 256) lnm[i] = nmap_g[(size_t)g * NPG + i];
    for (int i = tid; i < K1V; i += 256) lda[i] = 0;
    if (tid == 0) lcnt = 0;
    __syncthreads();
    const int4* s4 = (const int4*)(esrc + g * EPG + q * ESEG);
    const int4* d4 = (const int4*)(edst + g * EPG + q * ESEG);
    for (int i = tid; i < ESEG / 4; i += 256) {
        int4 ss = s4[i]; int4 dd = d4[i];
        int sa[4] = { ss.x & MSK, ss.y & MSK, ss.z & MSK, ss.w & MSK };
        int da[4] = { dd.x & MSK, dd.y & MSK, dd.z & MSK, dd.w & MSK };
        #pragma unroll
        for (int r = 0; r < 4; r++) {
            int s2 = lnm[sa[r]], d2 = lnm[da[r]];
            if (s2 >= 0 && d2 >= 0) {
                int p = atomicAdd(&lcnt, 1);
                if (p < QCAP) { pbuf[p] = s2 | (d2 << 16); atomicAdd(&lda[d2], 1); }
            }
        }
    }
    __syncthreads();
    int cnt = lcnt < QCAP ? lcnt : QCAP;
    if (tid == 0) eqcnt[bid] = cnt;
    for (int i = tid; i < cnt; i += 256) epair[(size_t)bid * QCAP + i] = pbuf[i];
    for (int i = tid; i < K1V; i += 256) ldegp[(size_t)bid * K1V + i] = lda[i];
}

// ===== K8: per-graph CSR scan + edge placement =====
__global__ __launch_bounds__(512) void k_csr(const int* __restrict__ ldegp,
                                             const int* __restrict__ eqcnt,
                                             const int* __restrict__ epair,
                                             int* __restrict__ srcs2,
                                             int* __restrict__ rs2, int* __restrict__ ic2,
                                             float* __restrict__ dfull2,
                                             float* __restrict__ dinv2) {
    __shared__ int cur[K1V];
    __shared__ u32 wsum[8];
    const int b = blockIdx.x, tid = threadIdx.x;
    const int lane = tid & 63, wv = tid >> 6;
    int dv = 0;
    #pragma unroll
    for (int q = 0; q < NQ; q++) dv += ldegp[(size_t)(b * NQ + q) * K1V + tid];
    u32 inc = (u32)dv;
    #pragma unroll
    for (int off = 1; off < 64; off <<= 1) {
        u32 v = __shfl_up(inc, off);
        if (lane >= off) inc += v;
    }
    if (lane == 63) wsum[wv] = inc;
    __syncthreads();
    if (tid == 0) { u32 run = 0; for (int w2 = 0; w2 < 8; w2++) { u32 v = wsum[w2]; wsum[w2] = run; run += v; } }
    __syncthreads();
    int excl = (int)(wsum[wv] + inc - (u32)dv);
    int n = b * K1V + tid;
    rs2[n] = b * SCAP + excl;
    ic2[n] = dv;
    float df = (float)dv + 1.0f;
    dfull2[n] = df;
    dinv2[n] = rsqrtf(df);
    cur[tid] = excl;
    __syncthreads();
    for (int q = 0; q < NQ; q++) {
        int cnt = eqcnt[b * NQ + q];
        for (int i = tid; i < cnt; i += 512) {
            int pk = epair[(size_t)(b * NQ + q) * QCAP + i];
            int s2 = pk & 0xffff, d2 = pk >> 16;
            int pos = atomicAdd(&cur[d2], 1);
            srcs2[(size_t)b * SCAP + pos] = b * K1V + s2;
        }
    }
}

// ============ hw = hp @ W2, hp recomputed from (ulist, tg1) ============
#define MM_ROWS 32
__global__ __launch_bounds__(256) void k_matmul(
    const float* __restrict__ ulist, const float* __restrict__ tg1,
    const float* __restrict__ W1, const float* __restrict__ b1,
    const float* __restrict__ W2, float* __restrict__ hw)
{
    __shared__ float lh[MM_ROWS * HID];
    __shared__ float lu[MM_ROWS], lg[MM_ROWS];
    __shared__ float lw1[HID], lb1[HID];
    int row0 = blockIdx.x * MM_ROWS, tid = threadIdx.x;
    if (tid < MM_ROWS) { lu[tid] = ulist[row0 + tid]; lg[tid] = tg1[row0 + tid]; }
    if (tid < HID) { lw1[tid] = W1[tid]; lb1[tid] = b1[tid]; }
    __syncthreads();
    for (int idx = tid; idx < MM_ROWS * HID; idx += 256) {
        int j = idx >> 7, c = idx & 127;
        lh[idx] = frelu(fmaf(lw1[c], lu[j], lb1[c])) * lg[j];
    }
    __syncthreads();
    int c = tid & 127, half = tid >> 7;
    float acc[16];
    #pragma unroll
    for (int r = 0; r < 16; r++) acc[r] = 0.f;
    for (int k = 0; k < HID; k++) {
        float w = W2[k * HID + c];
        #pragma unroll
        for (int r = 0; r < 16; r++) acc[r] = fmaf(lh[(half * 16 + r) * HID + k], w, acc[r]);
    }
    #pragma unroll
    for (int r = 0; r < 16; r++) hw[(size_t)(row0 + half * 16 + r) * HID + c] = acc[r];
}

// ====== stage-2 GCN via CSR pull, fused bias/relu/score ======
__global__ __launch_bounds__(256) void k_pull2(
    const int* __restrict__ srcs2, const int* __restrict__ rs2, const int* __restrict__ ic2,
    const float* __restrict__ dfull2, const float* __restrict__ dinv2,
    const float* __restrict__ hw, const float* __restrict__ b2,
    const float* __restrict__ sW2, const float* __restrict__ sb2,
    float* __restrict__ h2, float* __restrict__ ds02, float* __restrict__ sc2i)
{
    int node = blockIdx.x * 4 + (threadIdx.x >> 6);
    int lane = threadIdx.x & 63;
    int rs = rs2[node], cnt = ic2[node];
    float a0 = 0.f, a1 = 0.f;
    for (int j = 0; j < cnt; j++) {
        int s = srcs2[rs + j];
        float w = dinv2[s];
        a0 = fmaf(w, hw[(size_t)s * HID + lane], a0);
        a1 = fmaf(w, hw[(size_t)s * HID + 64 + lane], a1);
    }
    float df = dfull2[node], di = dinv2[node];
    float h0 = frelu(a0 * di + hw[(size_t)node * HID + lane] / df + b2[lane]);
    float h1 = frelu(a1 * di + hw[(size_t)node * HID + 64 + lane] / df + b2[lane + 64]);
    h2[(size_t)node * HID + lane] = h0;
    h2[(size_t)node * HID + 64 + lane] = h1;
    float dot = h0 * sW2[lane] + h1 * sW2[lane + 64];
    #pragma unroll
    for (int o = 32; o > 0; o >>= 1) dot += __shfl_down(dot, o);
    if (lane == 0) {
        ds02[node] = di * dot;
        sc2i[node] = dot / df + sb2[0];
    }
}

// ====== stage-2: finalize scores, radix-select top-128, pooled readout ======
__global__ __launch_bounds__(256) void k_topk2c(
    const int* __restrict__ srcs2, const int* __restrict__ rs2, const int* __restrict__ ic2,
    const float* __restrict__ dinv2, const float* __restrict__ ds02,
    const float* __restrict__ sc2i, const float* __restrict__ h2,
    float* __restrict__ x2b)
{
    __shared__ float sv[K1V];
    __shared__ u32   skey[K1V];
    __shared__ u32   hist[256], misc[2], wsum[4];
    __shared__ int   plist[K2V];
    __shared__ float tl[K2V];
    __shared__ float rmx[HID], rsm[HID];
    __shared__ int   scnt;
    const int b = blockIdx.x, tid = threadIdx.x;
    const int lane = tid & 63, wv = tid >> 6;
    if (tid == 0) scnt = 0;
    for (int r = tid; r < K1V; r += 256) {
        int n = b * K1V + r;
        int rs = rs2[n], cnt = ic2[n];
        float acc = 0.f;
        for (int j = 0; j < cnt; j++) acc += ds02[srcs2[rs + j]];
        float sc = sc2i[n] + dinv2[n] * acc;
        sv[r] = sc; skey[r] = f2key(sc);
    }
    __syncthreads();
    u32 tau; int R;
    radix_top<K1V, 256>(skey, K2V, hist, misc, tau, R);
    {
        int e0 = tid * 2, e1 = e0 + 1;
        u32 k0 = skey[e0], k1 = skey[e1];
        int q0 = (k0 == tau) ? 1 : 0, q1 = (k1 == tau) ? 1 : 0;
        u32 pairv = (u32)(q0 + q1);
        u32 inc = pairv;
        #pragma unroll
        for (int off = 1; off < 64; off <<= 1) {
            u32 v = __shfl_up(inc, off);
            if (lane >= off) inc += v;
        }
        if (lane == 63) wsum[wv] = inc;
        __syncthreads();
        if (tid == 0) { u32 run = 0; for (int w2 = 0; w2 < 4; w2++) { u32 v = wsum[w2]; wsum[w2] = run; run += v; } }
        __syncthreads();
        u32 base = wsum[wv] + inc - pairv;
        bool sel0 = (k0 > tau) || (q0 && base < (u32)R);
        bool sel1 = (k1 > tau) || (q1 && (base + (u32)q0) < (u32)R);
        if (sel0) { int pos = atomicAdd(&scnt, 1); plist[pos] = b * K1V + e0; tl[pos] = tanhf(sv[e0]); }
        if (sel1) { int pos = atomicAdd(&scnt, 1); plist[pos] = b * K1V + e1; tl[pos] = tanhf(sv[e1]); }
        __syncthreads();
    }
    int c = tid & 127, h = tid >> 7;
    float mx = -INFINITY, sm = 0.f;
    for (int j = h; j < K2V; j += 2) {
        float v = h2[(size_t)plist[j] * HID + c] * tl[j];
        mx = fmaxf(mx, v); sm += v;
    }
    if (h == 1) { rmx[c] = mx; rsm[c] = sm; }
    __syncthreads();
    if (h == 0) {
        mx = fmaxf(mx, rmx[c]); sm += rsm[c];
        x2b[b * 2 * HID + c] = mx;
        x2b[b * 2 * HID + HID + c] = sm / (float)K2V;
    }
}

// ============ head MLP + log_softmax ============
__global__ __launch_bounds__(128) void k_head(
    const float* __restrict__ x1, const float* __restrict__ x2,
    const float* __restrict__ gi,
    const float* __restrict__ l1W, const float* __restrict__ l1b,
    const float* __restrict__ l2W, const float* __restrict__ l2b,
    const float* __restrict__ l3W, const float* __restrict__ l3b,
    float* __restrict__ out)
{
    __shared__ float z[266], z1[HID], z2[64], z3[32], red[2];
    int b = blockIdx.x, t = threadIdx.x;
    for (int i = t; i < 256; i += 128) z[i] = x1[b * 256 + i] + x2[b * 256 + i];
    if (t < 10) z[256 + t] = gi[b * 10 + t];
    __syncthreads();
    float acc = l1b[t];
    for (int k = 0; k < 266; k++) acc = fmaf(z[k], l1W[k * 128 + t], acc);
    z1[t] = frelu(acc);
    __syncthreads();
    if (t < 64) {
        float a2 = l2b[t];
        for (int k = 0; k < 128; k++) a2 = fmaf(z1[k], l2W[k * 64 + t], a2);
        z2[t] = frelu(a2);
    }
    __syncthreads();
    if (t < 32) {
        float a3 = l3b[t];
        for (int k = 0; k < 64; k++) a3 = fmaf(z2[k], l3W[k * 32 + t], a3);
        z3[t] = a3;
    }
    __syncthreads();
    if (t == 0) {
        float m = -INFINITY;
        for (int c = 0; c < 32; c++) m = fmaxf(m, z3[c]);
        float s = 0.f;
        for (int c = 0; c < 32; c++) s += expf(z3[c] - m);
        red[0] = m; red[1] = logf(s);
    }
    __syncthreads();
    if (t < 32) out[b * 32 + t] = z3[t] - red[0] - red[1];
}

// ============ launch ============
extern "C" void kernel_launch(void* const* d_in, const int* in_sizes, int n_in,
                              void* d_out, int out_size, void* d_ws, size_t ws_size,
                              hipStream_t stream) {
    const float* x    = (const float*)d_in[0];
    const int*   esrc = (const int*)d_in[1];
    const int*   edst = (const int*)d_in[2];
    const float* gi   = (const float*)d_in[3];
    const float* W1   = (const float*)d_in[4];
    const float* b1   = (const float*)d_in[5];
    const float* sW1  = (const float*)d_in[6];
    const float* sb1  = (const float*)d_in[7];
    const float* W2   = (const float*)d_in[8];
    const float* b2   = (const float*)d_in[9];
    const float* sW2  = (const float*)d_in[10];
    const float* sb2  = (const float*)d_in[11];
    const float* l1W  = (const float*)d_in[12];
    const float* l1b  = (const float*)d_in[13];
    const float* l2W  = (const float*)d_in[14];
    const float* l2b  = (const float*)d_in[15];
    const float* l3W  = (const float*)d_in[16];
    const float* l3b  = (const float*)d_in[17];
    float* out = (float*)d_out;

    char* p = (char*)d_ws;
    auto alloc = [&](size_t bytes) {
        char* r = p;
        p += (bytes + 255) & ~size_t(255);
        return (void*)r;
    };
    int*   degp   = (int*)alloc((size_t)NB * NQ * NPG * 4);     // 4MB
    float* df_g   = (float*)alloc((size_t)NB * NPG * 4);
    float* di_g   = (float*)alloc((size_t)NB * NPG * 4);
    float* dx_g   = (float*)alloc((size_t)NB * NPG * 4);
    float* tp     = (float*)alloc((size_t)NB * NQ * NPG * 4);   // 4MB
    float* u_g    = (float*)alloc((size_t)NB * NPG * 4);
    float* ds01_g = (float*)alloc((size_t)NB * NPG * 4);
    float* sci_g  = (float*)alloc((size_t)NB * NPG * 4);
    float* scp    = (float*)alloc((size_t)NB * NQ * NPG * 4);   // 4MB
    int*   nmap_g = (int*)alloc((size_t)NB * NPG * 4);
    float* ulist  = (float*)alloc((size_t)N1 * 4);
    float* tg1    = (float*)alloc((size_t)N1 * 4);
    float* x1b    = (float*)alloc((size_t)NB * 256 * 4);
    float* x2b    = (float*)alloc((size_t)NB * 256 * 4);
    int*   epair  = (int*)alloc((size_t)NB * NQ * QCAP * 4);
    int*   eqcnt  = (int*)alloc((size_t)NB * NQ * 4);
    int*   ldegp  = (int*)alloc((size_t)NB * NQ * K1V * 4);     // 1MB
    int*   srcs2  = (int*)alloc((size_t)NB * SCAP * 4);
    int*   rs2    = (int*)alloc((size_t)N1 * 4);
    int*   ic2    = (int*)alloc((size_t)N1 * 4);
    float* dfull2 = (float*)alloc((size_t)N1 * 4);
    float* dinv2  = (float*)alloc((size_t)N1 * 4);
    float* hw     = (float*)alloc((size_t)N1 * HID * 4);        // 16MB
    float* h2     = (float*)alloc((size_t)N1 * HID * 4);        // 16MB
    float* ds02   = (float*)alloc((size_t)N1 * 4);
    float* sc2i   = (float*)alloc((size_t)N1 * 4);

    // stage 1 (decomposed)
    k_deg8<<<NB * NQ, 256, 0, stream>>>(edst, degp);
    k_nodeA<<<NB * NPG / 256, 256, 0, stream>>>(x, degp, df_g, di_g, dx_g);
    k_fsweep<<<NB * NQ, 256, 0, stream>>>(esrc, edst, dx_g, tp);
    k_nodeB<<<NB * NPG / 256, 256, 0, stream>>>(x, tp, df_g, di_g, W1, b1, sW1, sb1,
                                                u_g, ds01_g, sci_g);
    k_fsweep<<<NB * NQ, 256, 0, stream>>>(esrc, edst, ds01_g, scp);
    k_select<<<NB, 1024, 0, stream>>>(sci_g, di_g, scp, u_g, W1, b1,
                                      ulist, tg1, x1b, nmap_g);
    k_compact8<<<NB * NQ, 256, 0, stream>>>(esrc, edst, nmap_g, epair, eqcnt, ldegp);
    k_csr<<<NB, 512, 0, stream>>>(ldegp, eqcnt, epair, srcs2, rs2, ic2, dfull2, dinv2);

    // stage 2
    k_matmul<<<N1 / MM_ROWS, 256, 0, stream>>>(ulist, tg1, W1, b1, W2, hw);
    k_pull2<<<N1 / 4, 256, 0, stream>>>(srcs2, rs2, ic2, dfull2, dinv2, hw,
                                        b2, sW2, sb2, h2, ds02, sc2i);
    k_topk2c<<<NB, 256, 0, stream>>>(srcs2, rs2, ic2, dinv2, ds02, sc2i, h2, x2b);

    // head
    k_head<<<NB, 128, 0, stream>>>(x1b, x2b, gi, l1W, l1b, l2W, l2b, l3W, l3b, out);
}

// Round 6
// 145.907 us; speedup vs baseline: 4.4205x; 1.0003x over previous
//
#include <hip/hip_runtime.h>
#include <math.h>

#define NB    64
#define NPG   2048      // nodes per graph
#define EPG   16384     // edges per graph
#define HID   128
#define K1V   512
#define K2V   128
#define N1    32768     // NB*K1V
#define SCAP  2048      // per-graph surviving-edge capacity
#define MSK   (NPG - 1)
#define NQ    8         // edge segments per graph
#define ESEG  (EPG / NQ)   // 2048
#define QCAP  256       // per-segment survivor capacity (E~128, sigma~11)

typedef unsigned int u32;

static __device__ __forceinline__ float frelu(float v) { return v > 0.f ? v : 0.f; }

// monotone float -> uint key (larger float => larger key)
static __device__ __forceinline__ u32 f2key(float f) {
    u32 u = __float_as_uint(f);
    return u ^ ((u >> 31) ? 0xFFFFFFFFu : 0x80000000u);
}

// Radix-select the K-th largest key among N LDS keys.
template <int N, int T>
static __device__ __forceinline__ void radix_top(const u32* __restrict__ key, int K,
                                                 u32* hist, u32* misc,
                                                 u32& tau, int& R) {
    const int tid = threadIdx.x;
    if (tid == 0) { misc[0] = 0u; misc[1] = (u32)K; }
    __syncthreads();
    #pragma unroll
    for (int p = 0; p < 4; p++) {
        const int shift = 24 - 8 * p;
        for (int i = tid; i < 256; i += T) hist[i] = 0u;
        __syncthreads();
        const u32 prefix = misc[0];
        const u32 need   = misc[1];
        for (int i = tid; i < N; i += T) {
            u32 k = key[i];
            bool ok = (p == 0) || ((k >> (shift + 8)) == prefix);
            if (ok) atomicAdd(&hist[(k >> shift) & 255u], 1u);
        }
        __syncthreads();
        if (tid < 64) {
            const int lane = tid;
            u32 c0 = hist[4 * lane + 0], c1 = hist[4 * lane + 1];
            u32 c2 = hist[4 * lane + 2], c3 = hist[4 * lane + 3];
            u32 local = c0 + c1 + c2 + c3;
            u32 inc = local;
            #pragma unroll
            for (int off = 1; off < 64; off <<= 1) {
                u32 v = __shfl_down(inc, off);
                if (lane + off < 64) inc += v;
            }
            u32 excl = inc - local;
            u32 ge3 = excl + c3, ge2 = ge3 + c2, ge1 = ge2 + c1, ge0 = ge1 + c0;
            int selb = -1; u32 gt = 0;
            if      (ge3 >= need && excl < need) { selb = 4 * lane + 3; gt = excl; }
            else if (ge2 >= need && ge3  < need) { selb = 4 * lane + 2; gt = ge3; }
            else if (ge1 >= need && ge2  < need) { selb = 4 * lane + 1; gt = ge2; }
            else if (ge0 >= need && ge1  < need) { selb = 4 * lane + 0; gt = ge1; }
            if (selb >= 0) { misc[0] = (prefix << 8) | (u32)selb; misc[1] = need - gt; }
        }
        __syncthreads();
    }
    tau = misc[0];
    R = (int)misc[1];
}

// ===== K1: per-segment degree histogram (512 blocks = 8/graph) =====
__global__ __launch_bounds__(256) void k_deg8(const int* __restrict__ edst,
                                              int* __restrict__ degp) {
    __shared__ int cnt[NPG];
    const int bid = blockIdx.x, tid = threadIdx.x;
    const int g = bid >> 3, q = bid & 7;
    for (int i = tid; i < NPG; i += 256) cnt[i] = 0;
    __syncthreads();
    const int4* d4 = (const int4*)(edst + g * EPG + q * ESEG);
    for (int i = tid; i < ESEG / 4; i += 256) {
        int4 dd = d4[i];
        atomicAdd(&cnt[dd.x & MSK], 1); atomicAdd(&cnt[dd.y & MSK], 1);
        atomicAdd(&cnt[dd.z & MSK], 1); atomicAdd(&cnt[dd.w & MSK], 1);
    }
    __syncthreads();
    int4* op = (int4*)(degp + (size_t)bid * NPG);
    const int4* cp = (const int4*)cnt;
    for (int i = tid; i < NPG / 4; i += 256) op[i] = cp[i];
}

// ===== K2: node pass A: deg reduce -> df, dinv, dx =====
__global__ __launch_bounds__(256) void k_nodeA(const float* __restrict__ x,
                                               const int* __restrict__ degp,
                                               float* __restrict__ df_g,
                                               float* __restrict__ di_g,
                                               float* __restrict__ dx_g) {
    int i = blockIdx.x * 256 + threadIdx.x;
    int g = i >> 11, loc = i & MSK;
    int deg = 0;
    #pragma unroll
    for (int q = 0; q < NQ; q++) deg += degp[(size_t)(g * NQ + q) * NPG + loc];
    float df = (float)deg + 1.0f;
    float di = rsqrtf(df);
    df_g[i] = df; di_g[i] = di; dx_g[i] = di * x[i];
}

// ===== K3/K5: per-segment scatter-add sweep: out_partial[d] += val[s] =====
__global__ __launch_bounds__(256) void k_fsweep(const int* __restrict__ esrc,
                                                const int* __restrict__ edst,
                                                const float* __restrict__ val_g,
                                                float* __restrict__ outp) {
    __shared__ float lv[NPG];
    __shared__ float acc[NPG];
    const int bid = blockIdx.x, tid = threadIdx.x;
    const int g = bid >> 3, q = bid & 7;
    for (int i = tid; i < NPG; i += 256) { lv[i] = val_g[(size_t)g * NPG + i]; acc[i] = 0.f; }
    __syncthreads();
    const int4* s4 = (const int4*)(esrc + g * EPG + q * ESEG);
    const int4* d4 = (const int4*)(edst + g * EPG + q * ESEG);
    for (int i = tid; i < ESEG / 4; i += 256) {
        int4 ss = s4[i]; int4 dd = d4[i];
        atomicAdd(&acc[dd.x & MSK], lv[ss.x & MSK]);
        atomicAdd(&acc[dd.y & MSK], lv[ss.y & MSK]);
        atomicAdd(&acc[dd.z & MSK], lv[ss.z & MSK]);
        atomicAdd(&acc[dd.w & MSK], lv[ss.w & MSK]);
    }
    __syncthreads();
    float4* op = (float4*)(outp + (size_t)bid * NPG);
    const float4* ap = (const float4*)acc;
    for (int i = tid; i < NPG / 4; i += 256) op[i] = ap[i];
}

// ===== K4: node pass B: t reduce -> u, MLP -> ds01, sc_init =====
__global__ __launch_bounds__(256) void k_nodeB(const float* __restrict__ x,
                                               const float* __restrict__ tp,
                                               const float* __restrict__ df_g,
                                               const float* __restrict__ di_g,
                                               const float* __restrict__ W1,
                                               const float* __restrict__ b1,
                                               const float* __restrict__ sW1,
                                               const float* __restrict__ sb1,
                                               float* __restrict__ u_g,
                                               float* __restrict__ ds01_g,
                                               float* __restrict__ sci_g) {
    __shared__ float lw[HID], lbb[HID], lsw[HID];
    const int tid = threadIdx.x;
    if (tid < HID) { lw[tid] = W1[tid]; lbb[tid] = b1[tid]; lsw[tid] = sW1[tid]; }
    __syncthreads();
    int i = blockIdx.x * 256 + tid;
    int g = i >> 11, loc = i & MSK;
    float t = 0.f;
    #pragma unroll
    for (int q = 0; q < NQ; q++) t += tp[(size_t)(g * NQ + q) * NPG + loc];
    float df = df_g[i], di = di_g[i];
    float u = t * di + x[i] / df;
    float s = 0.f;
    #pragma unroll 8
    for (int c = 0; c < HID; c++) s += frelu(fmaf(lw[c], u, lbb[c])) * lsw[c];
    u_g[i] = u;
    ds01_g[i] = di * s;
    sci_g[i] = s / df + sb1[0];
}

// ===== K6: per-graph: score finalize, radix top-512, nmap, readout1 =====
__global__ __launch_bounds__(1024) void k_select(
    const float* __restrict__ sci_g, const float* __restrict__ di_g,
    const float* __restrict__ scp, const float* __restrict__ u_g,
    const float* __restrict__ W1, const float* __restrict__ b1,
    float* __restrict__ ulist, float* __restrict__ tg1, float* __restrict__ x1b,
    int* __restrict__ nmap_g)
{
    __shared__ float lsc[NPG];
    __shared__ u32   lkey[NPG];
    __shared__ int   ln[NPG];
    __shared__ float ul[K1V], tgl[K1V];
    __shared__ int   sellist[K1V];
    __shared__ u32   hist[256], misc[2], wsum[16];
    __shared__ int   scnt;
    __shared__ float lw[HID], lbb[HID];
    const int b = blockIdx.x, tid = threadIdx.x;
    const int lane = tid & 63, wv = tid >> 6;

    for (int i = tid; i < NPG; i += 1024) {
        float a = 0.f;
        #pragma unroll
        for (int q = 0; q < NQ; q++) a += scp[(size_t)(b * NQ + q) * NPG + i];
        float sc = sci_g[(size_t)b * NPG + i] + di_g[(size_t)b * NPG + i] * a;
        lsc[i] = sc;
        lkey[i] = f2key(sc);
        ln[i] = -1;
    }
    if (tid < HID) { lw[tid] = W1[tid]; lbb[tid] = b1[tid]; }
    if (tid == 0) scnt = 0;
    __syncthreads();

    u32 tau; int R;
    radix_top<NPG, 1024>(lkey, K1V, hist, misc, tau, R);

    // stable tie rank (lowest index first)
    {
        int e0 = tid * 2, e1 = e0 + 1;
        u32 k0 = lkey[e0], k1 = lkey[e1];
        int q0 = (k0 == tau) ? 1 : 0, q1 = (k1 == tau) ? 1 : 0;
        u32 pairv = (u32)(q0 + q1);
        u32 inc = pairv;
        #pragma unroll
        for (int off = 1; off < 64; off <<= 1) {
            u32 v = __shfl_up(inc, off);
            if (lane >= off) inc += v;
        }
        if (lane == 63) wsum[wv] = inc;
        __syncthreads();
        if (tid == 0) { u32 run = 0; for (int w2 = 0; w2 < 16; w2++) { u32 v = wsum[w2]; wsum[w2] = run; run += v; } }
        __syncthreads();
        u32 base = wsum[wv] + inc - pairv;
        bool sel0 = (k0 > tau) || (q0 && base < (u32)R);
        bool sel1 = (k1 > tau) || (q1 && (base + (u32)q0) < (u32)R);
        if (sel0) { int pos = atomicAdd(&scnt, 1); sellist[pos] = e0; }
        if (sel1) { int pos = atomicAdd(&scnt, 1); sellist[pos] = e1; }
        __syncthreads();
    }

    if (tid < K1V) {
        int node = sellist[tid];
        float uu = u_g[(size_t)b * NPG + node];
        float g = tanhf(lsc[node]);
        ul[tid] = uu; tgl[tid] = g;
        ulist[b * K1V + tid] = uu;
        tg1[b * K1V + tid] = g;
        ln[node] = tid;
    }
    __syncthreads();
    for (int i = tid; i < NPG; i += 1024) nmap_g[(size_t)b * NPG + i] = ln[i];

    // readout1: reuse lkey as two 1024-float partial arrays
    float* rp = (float*)lkey;
    {
        int grp = tid >> 7, c = tid & 127;
        float w = lw[c], bb = lbb[c];
        float mx = -INFINITY, sm = 0.f;
        for (int j = grp; j < K1V; j += 8) {
            float v = frelu(fmaf(w, ul[j], bb)) * tgl[j];
            mx = fmaxf(mx, v); sm += v;
        }
        __syncthreads();
        rp[tid] = mx; rp[1024 + tid] = sm;
        __syncthreads();
        if (tid < HID) {
            float m2 = -INFINITY, s2 = 0.f;
            #pragma unroll
            for (int g2 = 0; g2 < 8; g2++) {
                m2 = fmaxf(m2, rp[g2 * 128 + tid]);
                s2 += rp[1024 + g2 * 128 + tid];
            }
            x1b[b * 2 * HID + tid] = m2;
            x1b[b * 2 * HID + HID + tid] = s2 / (float)K1V;
        }
    }
}

// ===== K7: per-segment edge compaction =====
__global__ __launch_bounds__(256) void k_compact8(const int* __restrict__ esrc,
                                                  const int* __restrict__ edst,
                                                  const int* __restrict__ nmap_g,
                                                  int* __restrict__ epair,
                                                  int* __restrict__ eqcnt,
                                                  int* __restrict__ ldegp) {
    __shared__ int lnm[NPG];
    __shared__ int pbuf[QCAP];
    __shared__ int lda[K1V];
    __shared__ int lcnt;
    const int bid = blockIdx.x, tid = threadIdx.x;
    const int g = bid >> 3, q = bid & 7;
    for (int i = tid; i < NPG; i += 256) lnm[i] = nmap_g[(size_t)g * NPG + i];
    for (int i = tid; i < K1V; i += 256) lda[i] = 0;
    if (tid == 0) lcnt = 0;
    __syncthreads();
    const int4* s4 = (const int4*)(esrc + g * EPG + q * ESEG);
    const int4* d4 = (const int4*)(edst + g * EPG + q * ESEG);
    for (int i = tid; i < ESEG / 4; i += 256) {
        int4 ss = s4[i]; int4 dd = d4[i];
        int sa[4] = { ss.x & MSK, ss.y & MSK, ss.z & MSK, ss.w & MSK };
        int da[4] = { dd.x & MSK, dd.y & MSK, dd.z & MSK, dd.w & MSK };
        #pragma unroll
        for (int r = 0; r < 4; r++) {
            int s2 = lnm[sa[r]], d2 = lnm[da[r]];
            if (s2 >= 0 && d2 >= 0) {
                int p = atomicAdd(&lcnt, 1);
                if (p < QCAP) { pbuf[p] = s2 | (d2 << 16); atomicAdd(&lda[d2], 1); }
            }
        }
    }
    __syncthreads();
    int cnt = lcnt < QCAP ? lcnt : QCAP;
    if (tid == 0) eqcnt[bid] = cnt;
    for (int i = tid; i < cnt; i += 256) epair[(size_t)bid * QCAP + i] = pbuf[i];
    for (int i = tid; i < K1V; i += 256) ldegp[(size_t)bid * K1V + i] = lda[i];
}

// ===== K8: per-graph CSR scan + edge placement =====
__global__ __launch_bounds__(512) void k_csr(const int* __restrict__ ldegp,
                                             const int* __restrict__ eqcnt,
                                             const int* __restrict__ epair,
                                             int* __restrict__ srcs2,
                                             int* __restrict__ rs2, int* __restrict__ ic2,
                                             float* __restrict__ dfull2,
                                             float* __restrict__ dinv2) {
    __shared__ int cur[K1V];
    __shared__ u32 wsum[8];
    const int b = blockIdx.x, tid = threadIdx.x;
    const int lane = tid & 63, wv = tid >> 6;
    int dv = 0;
    #pragma unroll
    for (int q = 0; q < NQ; q++) dv += ldegp[(size_t)(b * NQ + q) * K1V + tid];
    u32 inc = (u32)dv;
    #pragma unroll
    for (int off = 1; off < 64; off <<= 1) {
        u32 v = __shfl_up(inc, off);
        if (lane >= off) inc += v;
    }
    if (lane == 63) wsum[wv] = inc;
    __syncthreads();
    if (tid == 0) { u32 run = 0; for (int w2 = 0; w2 < 8; w2++) { u32 v = wsum[w2]; wsum[w2] = run; run += v; } }
    __syncthreads();
    int excl = (int)(wsum[wv] + inc - (u32)dv);
    int n = b * K1V + tid;
    rs2[n] = b * SCAP + excl;
    ic2[n] = dv;
    float df = (float)dv + 1.0f;
    dfull2[n] = df;
    dinv2[n] = rsqrtf(df);
    cur[tid] = excl;
    __syncthreads();
    for (int q = 0; q < NQ; q++) {
        int cnt = eqcnt[b * NQ + q];
        for (int i = tid; i < cnt; i += 512) {
            int pk = epair[(size_t)(b * NQ + q) * QCAP + i];
            int s2 = pk & 0xffff, d2 = pk >> 16;
            int pos = atomicAdd(&cur[d2], 1);
            srcs2[(size_t)b * SCAP + pos] = b * K1V + s2;
        }
    }
}

// ============ hw = hp @ W2 — register-tiled f32 GEMM ============
// 64 rows/block, 256 threads, thread = 8 rows x 4 cols register tile.
// lhT staged k-major (computed from u,g); W2 staged whole in LDS.
// K-accumulation order per output unchanged -> bitwise-identical results.
#define MM_ROWS 64
__global__ __launch_bounds__(256) void k_matmul(
    const float* __restrict__ ulist, const float* __restrict__ tg1,
    const float* __restrict__ W1, const float* __restrict__ b1,
    const float* __restrict__ W2, float* __restrict__ hw)
{
    __shared__ float lw2[HID * HID];      // 64 KB, [k][c]
    __shared__ float lhT[HID * MM_ROWS];  // 32 KB, [k][j]
    __shared__ float lu[MM_ROWS], lg[MM_ROWS];
    const int tid = threadIdx.x;
    const int row0 = blockIdx.x * MM_ROWS;

    if (tid < MM_ROWS) { lu[tid] = ulist[row0 + tid]; lg[tid] = tg1[row0 + tid]; }
    {
        const float4* w4 = (const float4*)W2;
        float4* l4 = (float4*)lw2;
        #pragma unroll
        for (int i = 0; i < 16; i++) l4[tid + 256 * i] = w4[tid + 256 * i];
    }
    __syncthreads();
    // compute lhT[k][j] = relu(W1[k]*u_j + b1[k]) * g_j   (conflict-free: j fastest)
    for (int idx = tid; idx < HID * MM_ROWS; idx += 256) {
        int k = idx >> 6, j = idx & 63;
        lhT[idx] = frelu(fmaf(W1[k], lu[j], b1[k])) * lg[j];
    }
    __syncthreads();

    const int cg = tid & 31;   // cols cg*4 .. cg*4+3
    const int rg = tid >> 5;   // rows rg*8 .. rg*8+7
    float acc[8][4];
    #pragma unroll
    for (int r = 0; r < 8; r++)
        #pragma unroll
        for (int c = 0; c < 4; c++) acc[r][c] = 0.f;

    const float4* lhT4 = (const float4*)lhT;  // [k][j/4], 16 per k
    const float4* lw24 = (const float4*)lw2;  // [k][c/4], 32 per k
    #pragma unroll 2
    for (int k = 0; k < HID; k++) {
        float4 h0 = lhT4[k * 16 + rg * 2];
        float4 h1 = lhT4[k * 16 + rg * 2 + 1];
        float4 w  = lw24[k * 32 + cg];
        float hr[8] = { h0.x, h0.y, h0.z, h0.w, h1.x, h1.y, h1.z, h1.w };
        float wc[4] = { w.x, w.y, w.z, w.w };
        #pragma unroll
        for (int r = 0; r < 8; r++)
            #pragma unroll
            for (int c = 0; c < 4; c++)
                acc[r][c] = fmaf(hr[r], wc[c], acc[r][c]);
    }
    #pragma unroll
    for (int r = 0; r < 8; r++) {
        float4 o; o.x = acc[r][0]; o.y = acc[r][1]; o.z = acc[r][2]; o.w = acc[r][3];
        *(float4*)&hw[(size_t)(row0 + rg * 8 + r) * HID + cg * 4] = o;
    }
}

// ====== stage-2 GCN via CSR pull, fused bias/relu/score ======
__global__ __launch_bounds__(256) void k_pull2(
    const int* __restrict__ srcs2, const int* __restrict__ rs2, const int* __restrict__ ic2,
    const float* __restrict__ dfull2, const float* __restrict__ dinv2,
    const float* __restrict__ hw, const float* __restrict__ b2,
    const float* __restrict__ sW2, const float* __restrict__ sb2,
    float* __restrict__ h2, float* __restrict__ ds02, float* __restrict__ sc2i)
{
    int node = blockIdx.x * 4 + (threadIdx.x >> 6);
    int lane = threadIdx.x & 63;
    int rs = rs2[node], cnt = ic2[node];
    float a0 = 0.f, a1 = 0.f;
    for (int j = 0; j < cnt; j++) {
        int s = srcs2[rs + j];
        float w = dinv2[s];
        a0 = fmaf(w, hw[(size_t)s * HID + lane], a0);
        a1 = fmaf(w, hw[(size_t)s * HID + 64 + lane], a1);
    }
    float df = dfull2[node], di = dinv2[node];
    float h0 = frelu(a0 * di + hw[(size_t)node * HID + lane] / df + b2[lane]);
    float h1 = frelu(a1 * di + hw[(size_t)node * HID + 64 + lane] / df + b2[lane + 64]);
    h2[(size_t)node * HID + lane] = h0;
    h2[(size_t)node * HID + 64 + lane] = h1;
    float dot = h0 * sW2[lane] + h1 * sW2[lane + 64];
    #pragma unroll
    for (int o = 32; o > 0; o >>= 1) dot += __shfl_down(dot, o);
    if (lane == 0) {
        ds02[node] = di * dot;
        sc2i[node] = dot / df + sb2[0];
    }
}

// ====== stage-2: finalize scores, radix-select top-128, pooled readout ======
__global__ __launch_bounds__(256) void k_topk2c(
    const int* __restrict__ srcs2, const int* __restrict__ rs2, const int* __restrict__ ic2,
    const float* __restrict__ dinv2, const float* __restrict__ ds02,
    const float* __restrict__ sc2i, const float* __restrict__ h2,
    float* __restrict__ x2b)
{
    __shared__ float sv[K1V];
    __shared__ u32   skey[K1V];
    __shared__ u32   hist[256], misc[2], wsum[4];
    __shared__ int   plist[K2V];
    __shared__ float tl[K2V];
    __shared__ float rmx[HID], rsm[HID];
    __shared__ int   scnt;
    const int b = blockIdx.x, tid = threadIdx.x;
    const int lane = tid & 63, wv = tid >> 6;
    if (tid == 0) scnt = 0;
    for (int r = tid; r < K1V; r += 256) {
        int n = b * K1V + r;
        int rs = rs2[n], cnt = ic2[n];
        float acc = 0.f;
        for (int j = 0; j < cnt; j++) acc += ds02[srcs2[rs + j]];
        float sc = sc2i[n] + dinv2[n] * acc;
        sv[r] = sc; skey[r] = f2key(sc);
    }
    __syncthreads();
    u32 tau; int R;
    radix_top<K1V, 256>(skey, K2V, hist, misc, tau, R);
    {
        int e0 = tid * 2, e1 = e0 + 1;
        u32 k0 = skey[e0], k1 = skey[e1];
        int q0 = (k0 == tau) ? 1 : 0, q1 = (k1 == tau) ? 1 : 0;
        u32 pairv = (u32)(q0 + q1);
        u32 inc = pairv;
        #pragma unroll
        for (int off = 1; off < 64; off <<= 1) {
            u32 v = __shfl_up(inc, off);
            if (lane >= off) inc += v;
        }
        if (lane == 63) wsum[wv] = inc;
        __syncthreads();
        if (tid == 0) { u32 run = 0; for (int w2 = 0; w2 < 4; w2++) { u32 v = wsum[w2]; wsum[w2] = run; run += v; } }
        __syncthreads();
        u32 base = wsum[wv] + inc - pairv;
        bool sel0 = (k0 > tau) || (q0 && base < (u32)R);
        bool sel1 = (k1 > tau) || (q1 && (base + (u32)q0) < (u32)R);
        if (sel0) { int pos = atomicAdd(&scnt, 1); plist[pos] = b * K1V + e0; tl[pos] = tanhf(sv[e0]); }
        if (sel1) { int pos = atomicAdd(&scnt, 1); plist[pos] = b * K1V + e1; tl[pos] = tanhf(sv[e1]); }
        __syncthreads();
    }
    int c = tid & 127, h = tid >> 7;
    float mx = -INFINITY, sm = 0.f;
    for (int j = h; j < K2V; j += 2) {
        float v = h2[(size_t)plist[j] * HID + c] * tl[j];
        mx = fmaxf(mx, v); sm += v;
    }
    if (h == 1) { rmx[c] = mx; rsm[c] = sm; }
    __syncthreads();
    if (h == 0) {
        mx = fmaxf(mx, rmx[c]); sm += rsm[c];
        x2b[b * 2 * HID + c] = mx;
        x2b[b * 2 * HID + HID + c] = sm / (float)K2V;
    }
}

// ============ head MLP + log_softmax ============
__global__ __launch_bounds__(128) void k_head(
    const float* __restrict__ x1, const float* __restrict__ x2,
    const float* __restrict__ gi,
    const float* __restrict__ l1W, const float* __restrict__ l1b,
    const float* __restrict__ l2W, const float* __restrict__ l2b,
    const float* __restrict__ l3W, const float* __restrict__ l3b,
    float* __restrict__ out)
{
    __shared__ float z[266], z1[HID], z2[64], z3[32], red[2];
    int b = blockIdx.x, t = threadIdx.x;
    for (int i = t; i < 256; i += 128) z[i] = x1[b * 256 + i] + x2[b * 256 + i];
    if (t < 10) z[256 + t] = gi[b * 10 + t];
    __syncthreads();
    float acc = l1b[t];
    for (int k = 0; k < 266; k++) acc = fmaf(z[k], l1W[k * 128 + t], acc);
    z1[t] = frelu(acc);
    __syncthreads();
    if (t < 64) {
        float a2 = l2b[t];
        for (int k = 0; k < 128; k++) a2 = fmaf(z1[k], l2W[k * 64 + t], a2);
        z2[t] = frelu(a2);
    }
    __syncthreads();
    if (t < 32) {
        float a3 = l3b[t];
        for (int k = 0; k < 64; k++) a3 = fmaf(z2[k], l3W[k * 32 + t], a3);
        z3[t] = a3;
    }
    __syncthreads();
    if (t == 0) {
        float m = -INFINITY;
        for (int c = 0; c < 32; c++) m = fmaxf(m, z3[c]);
        float s = 0.f;
        for (int c = 0; c < 32; c++) s += expf(z3[c] - m);
        red[0] = m; red[1] = logf(s);
    }
    __syncthreads();
    if (t < 32) out[b * 32 + t] = z3[t] - red[0] - red[1];
}

// ============ launch ============
extern "C" void kernel_launch(void* const* d_in, const int* in_sizes, int n_in,
                              void* d_out, int out_size, void* d_ws, size_t ws_size,
                              hipStream_t stream) {
    const float* x    = (const float*)d_in[0];
    const int*   esrc = (const int*)d_in[1];
    const int*   edst = (const int*)d_in[2];
    const float* gi   = (const float*)d_in[3];
    const float* W1   = (const float*)d_in[4];
    const float* b1   = (const float*)d_in[5];
    const float* sW1  = (const float*)d_in[6];
    const float* sb1  = (const float*)d_in[7];
    const float* W2   = (const float*)d_in[8];
    const float* b2   = (const float*)d_in[9];
    const float* sW2  = (const float*)d_in[10];
    const float* sb2  = (const float*)d_in[11];
    const float* l1W  = (const float*)d_in[12];
    const float* l1b  = (const float*)d_in[13];
    const float* l2W  = (const float*)d_in[14];
    const float* l2b  = (const float*)d_in[15];
    const float* l3W  = (const float*)d_in[16];
    const float* l3b  = (const float*)d_in[17];
    float* out = (float*)d_out;

    char* p = (char*)d_ws;
    auto alloc = [&](size_t bytes) {
        char* r = p;
        p += (bytes + 255) & ~size_t(255);
        return (void*)r;
    };
    int*   degp   = (int*)alloc((size_t)NB * NQ * NPG * 4);     // 4MB
    float* df_g   = (float*)alloc((size_t)NB * NPG * 4);
    float* di_g   = (float*)alloc((size_t)NB * NPG * 4);
    float* dx_g   = (float*)alloc((size_t)NB * NPG * 4);
    float* tp     = (float*)alloc((size_t)NB * NQ * NPG * 4);   // 4MB
    float* u_g    = (float*)alloc((size_t)NB * NPG * 4);
    float* ds01_g = (float*)alloc((size_t)NB * NPG * 4);
    float* sci_g  = (float*)alloc((size_t)NB * NPG * 4);
    float* scp    = (float*)alloc((size_t)NB * NQ * NPG * 4);   // 4MB
    int*   nmap_g = (int*)alloc((size_t)NB * NPG * 4);
    float* ulist  = (float*)alloc((size_t)N1 * 4);
    float* tg1    = (float*)alloc((size_t)N1 * 4);
    float* x1b    = (float*)alloc((size_t)NB * 256 * 4);
    float* x2b    = (float*)alloc((size_t)NB * 256 * 4);
    int*   epair  = (int*)alloc((size_t)NB * NQ * QCAP * 4);
    int*   eqcnt  = (int*)alloc((size_t)NB * NQ * 4);
    int*   ldegp  = (int*)alloc((size_t)NB * NQ * K1V * 4);     // 1MB
    int*   srcs2  = (int*)alloc((size_t)NB * SCAP * 4);
    int*   rs2    = (int*)alloc((size_t)N1 * 4);
    int*   ic2    = (int*)alloc((size_t)N1 * 4);
    float* dfull2 = (float*)alloc((size_t)N1 * 4);
    float* dinv2  = (float*)alloc((size_t)N1 * 4);
    float* hw     = (float*)alloc((size_t)N1 * HID * 4);        // 16MB
    float* h2     = (float*)alloc((size_t)N1 * HID * 4);        // 16MB
    float* ds02   = (float*)alloc((size_t)N1 * 4);
    float* sc2i   = (float*)alloc((size_t)N1 * 4);

    // stage 1 (decomposed)
    k_deg8<<<NB * NQ, 256, 0, stream>>>(edst, degp);
    k_nodeA<<<NB * NPG / 256, 256, 0, stream>>>(x, degp, df_g, di_g, dx_g);
    k_fsweep<<<NB * NQ, 256, 0, stream>>>(esrc, edst, dx_g, tp);
    k_nodeB<<<NB * NPG / 256, 256, 0, stream>>>(x, tp, df_g, di_g, W1, b1, sW1, sb1,
                                                u_g, ds01_g, sci_g);
    k_fsweep<<<NB * NQ, 256, 0, stream>>>(esrc, edst, ds01_g, scp);
    k_select<<<NB, 1024, 0, stream>>>(sci_g, di_g, scp, u_g, W1, b1,
                                      ulist, tg1, x1b, nmap_g);
    k_compact8<<<NB * NQ, 256, 0, stream>>>(esrc, edst, nmap_g, epair, eqcnt, ldegp);
    k_csr<<<NB, 512, 0, stream>>>(ldegp, eqcnt, epair, srcs2, rs2, ic2, dfull2, dinv2);

    // stage 2
    k_matmul<<<N1 / MM_ROWS, 256, 0, stream>>>(ulist, tg1, W1, b1, W2, hw);
    k_pull2<<<N1 / 4, 256, 0, stream>>>(srcs2, rs2, ic2, dfull2, dinv2, hw,
                                        b2, sW2, sb2, h2, ds02, sc2i);
    k_topk2c<<<NB, 256, 0, stream>>>(srcs2, rs2, ic2, dinv2, ds02, sc2i, h2, x2b);

    // head
    k_head<<<NB, 128, 0, stream>>>(x1b, x2b, gi, l1W, l1b, l2W, l2b, l3W, l3b, out);
}